// Round 8
// baseline (342.778 us; speedup 1.0000x reference)
//
#include <hip/hip_runtime.h>
#include <hip/hip_bf16.h>
#include <math.h>

#define B_ 2
#define T_ 2048
#define C_ 1024
#define H_ 16
#define HS_ 64
#define N_ROWS (B_*T_)   // 4096
#define MB (1024*1024)

typedef __attribute__((ext_vector_type(8))) short bf16x8;
typedef __attribute__((ext_vector_type(8))) unsigned short u16x8;
typedef __attribute__((ext_vector_type(4))) float floatx4;

static __device__ __forceinline__ unsigned short f2bf(float f) {
  union { float f; unsigned u; } v; v.f = f;
  unsigned r = v.u + 0x7fff + ((v.u >> 16) & 1);   // round-to-nearest-even
  return (unsigned short)(r >> 16);
}
static __device__ __forceinline__ float bf2f(unsigned short s) {
  union { unsigned u; float f; } v; v.u = ((unsigned)s) << 16;
  return v.f;
}

// ---------------- LayerNorm: one block per row, bf16 output ----------------
__global__ __launch_bounds__(256) void ln_kernel(
    const float* __restrict__ x, const float* __restrict__ g,
    const float* __restrict__ b, unsigned short* __restrict__ outb)
{
  const int row = blockIdx.x;
  const int tid = threadIdx.x;
  const float* xr = x + (size_t)row * C_;
  float4 xv = *reinterpret_cast<const float4*>(xr + tid * 4);
  float s  = xv.x + xv.y + xv.z + xv.w;
  float ss = xv.x*xv.x + xv.y*xv.y + xv.z*xv.z + xv.w*xv.w;
  #pragma unroll
  for (int off = 32; off > 0; off >>= 1) {
    s  += __shfl_down(s, off, 64);
    ss += __shfl_down(ss, off, 64);
  }
  __shared__ float rs[4], rss[4];
  __shared__ float smu, srstd;
  if ((tid & 63) == 0) { rs[tid >> 6] = s; rss[tid >> 6] = ss; }
  __syncthreads();
  if (tid == 0) {
    float S  = rs[0] + rs[1] + rs[2] + rs[3];
    float SS = rss[0] + rss[1] + rss[2] + rss[3];
    float mu  = S * (1.0f / C_);
    float var = SS * (1.0f / C_) - mu * mu;
    smu = mu; srstd = rsqrtf(var + 1e-5f);
  }
  __syncthreads();
  const float mu = smu, rstd = srstd;
  float4 gv = *reinterpret_cast<const float4*>(g + tid * 4);
  float4 bv = *reinterpret_cast<const float4*>(b + tid * 4);
  union { unsigned long long ll; unsigned short s[4]; } o;
  o.s[0] = f2bf((xv.x - mu) * rstd * gv.x + bv.x);
  o.s[1] = f2bf((xv.y - mu) * rstd * gv.y + bv.y);
  o.s[2] = f2bf((xv.z - mu) * rstd * gv.z + bv.z);
  o.s[3] = f2bf((xv.w - mu) * rstd * gv.w + bv.w);
  *reinterpret_cast<unsigned long long*>(outb + (size_t)row * C_ + tid * 4) = o.ll;
}

// ---------------- Transpose + cast: fp32 [R][Cc] -> bf16 [Cc][R], batched ---
__global__ __launch_bounds__(256) void transpose_cast(
    const float* __restrict__ in, unsigned short* __restrict__ out, int R, int Cc)
{
  __shared__ float tile[32][33];
  const int bz = blockIdx.z;
  in  += (size_t)bz * R * Cc;
  out += (size_t)bz * R * Cc;
  const int tx = threadIdx.x & 31;
  const int ty = threadIdx.x >> 5;    // 0..7
  const int c0 = blockIdx.x * 32, r0 = blockIdx.y * 32;
  #pragma unroll
  for (int j = 0; j < 4; ++j)
    tile[ty + j*8][tx] = in[(size_t)(r0 + ty + j*8) * Cc + c0 + tx];
  __syncthreads();
  #pragma unroll
  for (int j = 0; j < 4; ++j)
    out[(size_t)(c0 + ty + j*8) * R + r0 + tx] = f2bf(tile[tx][ty + j*8]);
}

// Fused QKV weight transpose: z in [0,48) -> which = z/16, head = z%16.
__global__ __launch_bounds__(256) void transpose_cast_qkv(
    const float* __restrict__ Wq, const float* __restrict__ Wk,
    const float* __restrict__ Wv, unsigned short* __restrict__ out)
{
  __shared__ float tile[32][33];
  const int z = blockIdx.z;
  const int which = z >> 4, h = z & 15;
  const float* in = (which == 0 ? Wq : which == 1 ? Wk : Wv) + (size_t)h * C_ * HS_;
  unsigned short* dst = out + (size_t)z * C_ * HS_;
  const int tx = threadIdx.x & 31;
  const int ty = threadIdx.x >> 5;
  const int c0 = blockIdx.x * 32, r0 = blockIdx.y * 32;
  #pragma unroll
  for (int j = 0; j < 4; ++j)
    tile[ty + j*8][tx] = in[(size_t)(r0 + ty + j*8) * HS_ + c0 + tx];
  __syncthreads();
  #pragma unroll
  for (int j = 0; j < 4; ++j)
    dst[(size_t)(c0 + ty + j*8) * C_ + r0 + tx] = f2bf(tile[tx][ty + j*8]);
}

// ========= 128x128 bf16 GEMM v4: 4 blocks/CU, single-barrier dbuf =========
// R7 post-mortem: v3's internal A/B proved TLP is the binding resource
// (identical kernel: W1 @2.0 blocks/CU >= 734 TF, QKV @1.5 = 542 TF;
// occupancy only 32%). v4 maximizes TLP: BM=BN=128, 256 thr (4 waves
// 2Mx2N, per-wave 64x64, acc[4][4] in AGPRs — v3 showed VGPR_Count 56,
// acc lives in AGPR, ~120 unified -> 4 waves/SIMD OK). LDS 32KB (2-deep
// dbuf) -> 4 blocks/CU (LDS would allow 5). Grids: QKV 768 (3/CU),
// W1/W2 1024 (4/CU) — all CUs balanced, 12-16 waves/CU vs 10.4.
// Loop/swizzle/staging identical to v3 (proven: 0 bank conflicts).
// Falsification: if this is null, the wall is LDS-array BW (512 B/MFMA
// at 64x64 wave-tile) -> R9 goes to 128x64 wave-tiles (384 B/MFMA).
template<bool RELU, bool HASB>
__global__ __launch_bounds__(256, 4) void gemm128(
    const unsigned short* __restrict__ A,   // [M][Kfull] bf16
    const unsigned short* __restrict__ Bt,  // [N][Kfull] bf16
    const float* __restrict__ bias,         // [N] fp32 (HASB)
    unsigned short* __restrict__ Cout,      // [z][M][N] bf16
    int M, int N, int Kfull, int Kh)
{
  __shared__ __align__(16) unsigned short Asl[2 * 4096];  // 2 x [128][32]  8KB
  __shared__ __align__(16) unsigned short Bsl[2 * 4096];  // 2 x [128][32]  8KB
  const int tid = threadIdx.x;
  const int w = tid >> 6, l = tid & 63;
  const int wm = w & 1, wn = w >> 1;          // 2M x 2N wave grid, 64x64/wave
  const int fr = l & 15, fq = l >> 4;
  const int m0 = blockIdx.x * 128, n0 = blockIdx.y * 128;
  const int z = blockIdx.z;

  const unsigned short* Aw = A  + (size_t)m0 * Kfull + (size_t)z * Kh;
  const unsigned short* Bw = Bt + (size_t)n0 * Kfull + (size_t)z * Kh;
  unsigned short* Cw = Cout + (size_t)z * M * N;

  // Staging (swizzled, R5/R7-verified): region[row][slot], slot holds
  // K-group g = (slot - (row>>1)) & 3; linear LDS dest (wave base +
  // lane*16B), per-lane pre-swizzled global K-group g. 4 waves cover 64
  // rows per load-slot -> 2 load-slots each for A and B (rows 0-63, 64-127).
  const int g    = ((l & 3) - ((l >> 3) & 3)) & 3;
  const int srow = w * 16 + (l >> 2);         // 0..63
  const unsigned short* ga0 = Aw + (size_t)srow * Kfull + g * 8;
  const unsigned short* ga1 = ga0 + (size_t)64 * Kfull;
  const unsigned short* gb0 = Bw + (size_t)srow * Kfull + g * 8;
  const unsigned short* gb1 = gb0 + (size_t)64 * Kfull;
  unsigned short* da0 = Asl + w * 512;
  unsigned short* db0 = Bsl + w * 512;

  const int Qmax = (Kh >> 5) - 1;   // K-halves - 1 (31 for Kh=1024)

  auto STAGE = [&](int q) {
    unsigned short* da = da0 + (q & 1) * 4096;
    unsigned short* db = db0 + (q & 1) * 4096;
    __builtin_amdgcn_global_load_lds(
        (const __attribute__((address_space(1))) void*)(ga0 + q * 32),
        (__attribute__((address_space(3))) void*)da, 16, 0, 0);
    __builtin_amdgcn_global_load_lds(
        (const __attribute__((address_space(1))) void*)(ga1 + q * 32),
        (__attribute__((address_space(3))) void*)(da + 2048), 16, 0, 0);
    __builtin_amdgcn_global_load_lds(
        (const __attribute__((address_space(1))) void*)(gb0 + q * 32),
        (__attribute__((address_space(3))) void*)db, 16, 0, 0);
    __builtin_amdgcn_global_load_lds(
        (const __attribute__((address_space(1))) void*)(gb1 + q * 32),
        (__attribute__((address_space(3))) void*)(db + 2048), 16, 0, 0);
  };

  // Fragment read offsets: slot = (fq + (row>>1)) & 3; row-base terms
  // (wm*64, wn*64, mf*16) are 0 mod 8 -> only fr affects the slot rotation.
  const int slot8 = ((fq + (fr >> 1)) & 3) * 8;
  const int aoff = (wm * 64 + fr) * 32 + slot8;   // + mf*512
  const int boff = (wn * 64 + fr) * 32 + slot8;   // + nf*512

  floatx4 acc[4][4] = {};

  STAGE(0);
  asm volatile("s_waitcnt vmcnt(0)" ::: "memory");
  __builtin_amdgcn_s_barrier();

  #pragma unroll 1
  for (int q = 0; q <= Qmax; ++q) {
    if (q < Qmax) STAGE(q + 1);          // into region (q+1)&1 (not being read)
    const unsigned short* Ar = Asl + (q & 1) * 4096;
    const unsigned short* Br = Bsl + (q & 1) * 4096;
    bf16x8 af[4], bfr[4];
    #pragma unroll
    for (int mf = 0; mf < 4; ++mf)
      af[mf]  = *(const bf16x8*)(Ar + aoff + mf * 512);
    #pragma unroll
    for (int nf = 0; nf < 4; ++nf)
      bfr[nf] = *(const bf16x8*)(Br + boff + nf * 512);
    __builtin_amdgcn_s_setprio(1);
    #pragma unroll
    for (int mf = 0; mf < 4; ++mf)
      #pragma unroll
      for (int nf = 0; nf < 4; ++nf)
        acc[mf][nf] = __builtin_amdgcn_mfma_f32_16x16x32_bf16(
            af[mf], bfr[nf], acc[mf][nf], 0, 0, 0);
    __builtin_amdgcn_s_setprio(0);
    if (q < Qmax) { asm volatile("s_waitcnt vmcnt(0)" ::: "memory"); }
    __builtin_amdgcn_s_barrier();
    // barrier semantics: (a) frag reads (lgkmcnt'd before MFMA) complete
    // before any wave's next STAGE overwrites this region; (b) vmcnt(0)
    // before barrier -> region (q+1)&1 fully written before it's read.
  }

  // Epilogue: bias / relu / bf16 store.
  #pragma unroll
  for (int nf = 0; nf < 4; ++nf) {
    const int col = n0 + wn * 64 + nf * 16 + fr;
    const float bv = HASB ? bias[col] : 0.0f;
    #pragma unroll
    for (int mf = 0; mf < 4; ++mf) {
      #pragma unroll
      for (int r = 0; r < 4; ++r) {
        const int row = m0 + wm * 64 + mf * 16 + fq * 4 + r;
        float v = acc[mf][nf][r] + bv;
        if (RELU) v = v > 0.0f ? v : 0.0f;
        Cw[(size_t)row * N + col] = f2bf(v);
      }
    }
  }
}

// ------------- bf16 MFMA GEMM (128^2 2-phase, R4-proven) — Wo only ---------
template<int TNB, bool OUTBF16, bool RELU, bool HASB, bool HASRES>
__global__ __launch_bounds__(256) void gemm_bf16(
    const unsigned short* __restrict__ A,   // [M][K] bf16
    const unsigned short* __restrict__ Bt,  // [N][K] bf16
    const float* __restrict__ bias,         // [N] fp32
    const unsigned short* __restrict__ res, // [M][N] bf16
    void* __restrict__ Cout,                // [M][N] fp32 or bf16
    int M, int N, int K)
{
  constexpr int NT = TNB / 32;              // B-tiles per wave: 4 or 2
  constexpr int WN = TNB / 2;               // wave n-extent: 64 or 32
  constexpr int LOADS = 4 + 2 * (TNB / 64); // gload_lds per thread per K-tile
  __shared__ unsigned short As[2][2][128 * 32];
  __shared__ unsigned short Bs[2][2][TNB * 32];
  const int tid  = threadIdx.x;
  const int lane = tid & 63;
  const int wave = tid >> 6;
  const int wm = wave & 1, wn = wave >> 1;
  const int m0 = blockIdx.x * 128, n0 = blockIdx.y * TNB;

  const int lrow = lane >> 2;
  const int lcol = (lane & 3) * 8;
  const int fr = lane & 15;
  const int fq = lane >> 4;

  floatx4 acc[4][NT] = {};

  const unsigned short* Aw = A  + (size_t)m0 * K;
  const unsigned short* Bw = Bt + (size_t)n0 * K;

  auto STAGE = [&](int bb, int k0) {
    #pragma unroll
    for (int half = 0; half < 2; ++half) {
      #pragma unroll
      for (int i = 0; i < 2; ++i) {
        const int rbase = i * 64 + wave * 16;
        const unsigned short* gp =
            Aw + (size_t)(rbase + lrow) * K + k0 + half * 32 + lcol;
        __builtin_amdgcn_global_load_lds(
            (const __attribute__((address_space(1))) void*)gp,
            (__attribute__((address_space(3))) void*)(As[bb][half] + rbase * 32),
            16, 0, 0);
      }
      #pragma unroll
      for (int i = 0; i < TNB / 64; ++i) {
        const int rbase = i * 64 + wave * 16;
        const unsigned short* gp =
            Bw + (size_t)(rbase + lrow) * K + k0 + half * 32 + lcol;
        __builtin_amdgcn_global_load_lds(
            (const __attribute__((address_space(1))) void*)gp,
            (__attribute__((address_space(3))) void*)(Bs[bb][half] + rbase * 32),
            16, 0, 0);
      }
    }
  };

  auto COMPUTE = [&](int bb) {
    #pragma unroll
    for (int half = 0; half < 2; ++half) {
      bf16x8 af[4], bfr[NT];
      #pragma unroll
      for (int t = 0; t < 4; ++t)
        af[t]  = *reinterpret_cast<const bf16x8*>(
            As[bb][half] + (wm*64 + t*16 + fr)*32 + fq*8);
      #pragma unroll
      for (int t = 0; t < NT; ++t)
        bfr[t] = *reinterpret_cast<const bf16x8*>(
            Bs[bb][half] + (wn*WN + t*16 + fr)*32 + fq*8);
      #pragma unroll
      for (int mt = 0; mt < 4; ++mt)
        #pragma unroll
        for (int nt = 0; nt < NT; ++nt)
          acc[mt][nt] = __builtin_amdgcn_mfma_f32_16x16x32_bf16(
              af[mt], bfr[nt], acc[mt][nt], 0, 0, 0);
    }
  };

  STAGE(0, 0);
  int bb = 0;
  for (int k0 = 64; k0 < K; k0 += 64) {
    STAGE(bb ^ 1, k0);                       // next tile: stays in flight
    asm volatile("s_waitcnt vmcnt(%0)" :: "n"(LOADS) : "memory");
    __builtin_amdgcn_s_barrier();            // tile bb fully in LDS, all waves
    COMPUTE(bb);
    __builtin_amdgcn_s_barrier();            // all waves done reading bb
    bb ^= 1;
  }
  asm volatile("s_waitcnt vmcnt(0)" ::: "memory");
  __builtin_amdgcn_s_barrier();
  COMPUTE(bb);

  #pragma unroll
  for (int nt = 0; nt < NT; ++nt) {
    const int col = n0 + wn*WN + nt*16 + fr;
    const float bv = HASB ? bias[col] : 0.0f;
    #pragma unroll
    for (int mt = 0; mt < 4; ++mt) {
      #pragma unroll
      for (int r = 0; r < 4; ++r) {
        const int row = m0 + wm*64 + mt*16 + fq*4 + r;
        float v = acc[mt][nt][r] + bv;
        if (RELU) v = v > 0.0f ? v : 0.0f;
        if (HASRES) v += bf2f(res[(size_t)row * N + col]);
        if (OUTBF16) ((unsigned short*)Cout)[(size_t)row * N + col] = f2bf(v);
        else         ((float*)Cout)[(size_t)row * N + col] = v;
      }
    }
  }
}

// -------- split-K reduce: out = sum_z p[z] + bias + res (all bf16 in) ------
template<int SPLITS>
__global__ __launch_bounds__(256) void splitk_reduce(
    const unsigned short* __restrict__ p,   // [SPLITS][M*N] bf16
    const float* __restrict__ bias, const unsigned short* __restrict__ res,
    float* __restrict__ out)
{
  const size_t i = ((size_t)blockIdx.x * 256 + threadIdx.x) * 4;
  const size_t MN = (size_t)N_ROWS * C_;
  float4 bv = *reinterpret_cast<const float4*>(bias + (i & (size_t)(C_ - 1)));
  float acc[4] = {bv.x, bv.y, bv.z, bv.w};
  {
    const unsigned short* rp = res + i;
    #pragma unroll
    for (int j = 0; j < 4; ++j) acc[j] += bf2f(rp[j]);
  }
  #pragma unroll
  for (int z = 0; z < SPLITS; ++z) {
    const unsigned short* pp = p + (size_t)z * MN + i;
    #pragma unroll
    for (int j = 0; j < 4; ++j) acc[j] += bf2f(pp[j]);
  }
  float4 o; o.x = acc[0]; o.y = acc[1]; o.z = acc[2]; o.w = acc[3];
  *reinterpret_cast<float4*>(out + i) = o;
}

// ---------------- V transpose: qkv V-part -> vt[bh][64 d][2048 t] bf16 -----
__global__ __launch_bounds__(256) void v_transpose(
    const unsigned short* __restrict__ qkv, unsigned short* __restrict__ vt)
{
  __shared__ __align__(16) unsigned short sT[64][72];
  const int st = blockIdx.x;        // s-tile of 64
  const int bh = blockIdx.y;
  const int b = bh >> 4, h = bh & 15;
  const int t = threadIdx.x;
  const int r = t >> 2, c0 = (t & 3) * 16;
  const unsigned short* src =
      qkv + (size_t)(b * T_ + st * 64 + r) * 3072 + 2048 + h * 64 + c0;
  *(u16x8*)&sT[r][c0]     = *(const u16x8*)src;
  *(u16x8*)&sT[r][c0 + 8] = *(const u16x8*)(src + 8);
  __syncthreads();
  const int d = t >> 2, sc = (t & 3) * 16;
  unsigned short v[16];
  #pragma unroll
  for (int j = 0; j < 16; ++j) v[j] = sT[sc + j][d];
  unsigned short* dst = vt + ((size_t)bh * 64 + d) * (size_t)T_ + st * 64 + sc;
  *(uint4*)dst       = *(uint4*)&v[0];
  *(uint4*)(dst + 8) = *(uint4*)&v[8];
}

// ---------------- MFMA flash attention v4 (unchanged from R2) --------------
__global__ __launch_bounds__(256, 3) void attn_mfma(
    const unsigned short* __restrict__ qkv,
    const unsigned short* __restrict__ vt,
    unsigned short* __restrict__ out)
{
  const int bh = blockIdx.x;
  const int qt = (int)(gridDim.y - 1) - (int)blockIdx.y;  // long blocks first
  const int b = bh >> 4, h = bh & 15;
  const int tid = threadIdx.x;
  const int w = tid >> 6;
  const int lane = tid & 63;
  const int l15 = lane & 15, fq = lane >> 4;
  const int t0 = qt * 64;
  const int q_row = t0 + w * 16 + l15;   // this lane's q column

  __shared__ __align__(16) unsigned short sK [128][72];   // [s][d]
  __shared__ __align__(16) unsigned short sVt[64][136];   // [d][s]
  __shared__ __align__(16) unsigned short sP [64][136];   // [q][s], wave-private rows

  const float c1 = 1.4426950408889634f / 32.0f;   // log2(e) * C^-0.5

  // Q fragment (dual-use A/B layout): Q[q_row][d = c*32 + fq*8 + j]
  bf16x8 aq[2];
  {
    const unsigned short* qp = qkv + (size_t)(b*T_ + q_row)*3072 + h*HS_ + fq*8;
    aq[0] = *(const bf16x8*)qp;
    aq[1] = *(const bf16x8*)(qp + 32);
  }

  const int nks = (qt >> 1) + 1;          // 128-wide K/V tiles

  // staging lane coords (K: 128 rows x 64 d; Vt: 64 rows x 128 s)
  const int kr = tid >> 1, kc = (tid & 1) * 32;
  const int vr = tid >> 2, vc = (tid & 3) * 32;
  const unsigned short* kp0 =
      qkv + (size_t)(b*T_ + kr)*3072 + C_ + h*HS_ + kc;
  const unsigned short* vp0 =
      vt + ((size_t)bh*64 + vr)*(size_t)T_ + vc;

  // prologue: load tile 0 and stage it (latency exposed once per block)
  u16x8 kg0, kg1, kg2, kg3, vg0, vg1, vg2, vg3;
  kg0 = *(const u16x8*)kp0;      kg1 = *(const u16x8*)(kp0 + 8);
  kg2 = *(const u16x8*)(kp0+16); kg3 = *(const u16x8*)(kp0 + 24);
  vg0 = *(const u16x8*)vp0;      vg1 = *(const u16x8*)(vp0 + 8);
  vg2 = *(const u16x8*)(vp0+16); vg3 = *(const u16x8*)(vp0 + 24);
  *(u16x8*)&sK [kr][kc]      = kg0; *(u16x8*)&sK [kr][kc + 8]  = kg1;
  *(u16x8*)&sK [kr][kc + 16] = kg2; *(u16x8*)&sK [kr][kc + 24] = kg3;
  *(u16x8*)&sVt[vr][vc]      = vg0; *(u16x8*)&sVt[vr][vc + 8]  = vg1;
  *(u16x8*)&sVt[vr][vc + 16] = vg2; *(u16x8*)&sVt[vr][vc + 24] = vg3;

  floatx4 oacc[4] = {};   // [dt]; C/D: col d = dt*16+l15, row q-local = fq*4+r
  float m_s = -3.0e38f, l_s = 0.0f;

  #pragma unroll 1
  for (int ks = 0; ks < nks; ++ks) {
    // publish tile ks (staged at prologue / bottom of previous iteration)
    asm volatile("s_waitcnt lgkmcnt(0)" ::: "memory");
    __builtin_amdgcn_s_barrier();

    // T14: issue tile ks+1 global loads now; they complete under the compute
    if (ks + 1 < nks) {
      const unsigned short* kp = kp0 + (size_t)(ks + 1) * (128 * 3072);
      kg0 = *(const u16x8*)kp;        kg1 = *(const u16x8*)(kp + 8);
      kg2 = *(const u16x8*)(kp + 16); kg3 = *(const u16x8*)(kp + 24);
      const unsigned short* vp = vp0 + (ks + 1) * 128;
      vg0 = *(const u16x8*)vp;        vg1 = *(const u16x8*)(vp + 8);
      vg2 = *(const u16x8*)(vp + 16); vg3 = *(const u16x8*)(vp + 24);
    }

    // S^T = K-tile · Q^T : D[m = s-local = st*16+fq*4+r][n = q-local = l15]
    floatx4 stacc[8] = {};
    __builtin_amdgcn_s_setprio(1);
    #pragma unroll
    for (int st = 0; st < 8; ++st) {
      bf16x8 ka = *(const bf16x8*)&sK[st*16 + l15][fq*8];
      bf16x8 kb = *(const bf16x8*)&sK[st*16 + l15][32 + fq*8];
      stacc[st] = __builtin_amdgcn_mfma_f32_16x16x32_bf16(ka, aq[0], stacc[st], 0, 0, 0);
      stacc[st] = __builtin_amdgcn_mfma_f32_16x16x32_bf16(kb, aq[1], stacc[st], 0, 0, 0);
    }
    __builtin_amdgcn_s_setprio(0);

    if (ks == nks - 1) {   // diagonal tile: mask s > q
      const int sbase = ks*128 + fq*4;
      #pragma unroll
      for (int st = 0; st < 8; ++st)
        #pragma unroll
        for (int r = 0; r < 4; ++r)
          if (sbase + st*16 + r > q_row) stacc[st][r] = -3.0e38f;
    }

    // online softmax over s for this lane's q: in-lane 32 + 2 shfl_xor
    float mx = -3.0e38f;
    #pragma unroll
    for (int st = 0; st < 8; ++st)
      #pragma unroll
      for (int r = 0; r < 4; ++r) mx = fmaxf(mx, stacc[st][r]);
    mx = fmaxf(mx, __shfl_xor(mx, 16, 64));
    mx = fmaxf(mx, __shfl_xor(mx, 32, 64));

    float mnew;
    if (__all((mx - m_s) * c1 <= 8.0f)) {
      mnew = m_s;                       // defer: keep old max, no rescale
    } else {
      mnew = fmaxf(m_s, mx);
      const float alpha = __builtin_amdgcn_exp2f((m_s - mnew) * c1);
      #pragma unroll
      for (int r = 0; r < 4; ++r) {
        const float ar = __shfl(alpha, fq*4 + r, 64);
        #pragma unroll
        for (int dt = 0; dt < 4; ++dt) oacc[dt][r] *= ar;
      }
      l_s *= alpha;
      m_s = mnew;
    }

    const float mc = mnew * c1;
    float sum = 0.0f;
    #pragma unroll
    for (int st = 0; st < 8; ++st) {
      unsigned pu[4];
      #pragma unroll
      for (int r = 0; r < 4; ++r) {
        const float p = __builtin_amdgcn_exp2f(stacc[st][r] * c1 - mc);
        sum += p;
        union { float f; unsigned u; } cv; cv.f = p;
        pu[r] = cv.u + 0x8000u;              // round-half-up to bf16
      }
      const unsigned lo = __builtin_amdgcn_perm(pu[1], pu[0], 0x07060302u);
      const unsigned hi = __builtin_amdgcn_perm(pu[3], pu[2], 0x07060302u);
      // P[q][s]: row = wave-private q, col = 4 consecutive s
      *(unsigned long long*)&sP[w*16 + l15][st*16 + fq*4] =
          ((unsigned long long)hi << 32) | lo;
    }
    sum += __shfl_xor(sum, 16, 64);
    sum += __shfl_xor(sum, 32, 64);
    l_s += sum;

    // PV: O[q][d] += P[q][s] · V[s][d]   (sP rows are wave-private: no barrier)
    __builtin_amdgcn_s_setprio(1);
    #pragma unroll
    for (int c = 0; c < 4; ++c) {
      bf16x8 ap = *(const bf16x8*)&sP[w*16 + l15][c*32 + fq*8];
      #pragma unroll
      for (int dt = 0; dt < 4; ++dt) {
        bf16x8 bv = *(const bf16x8*)&sVt[dt*16 + l15][c*32 + fq*8];
        oacc[dt] = __builtin_amdgcn_mfma_f32_16x16x32_bf16(ap, bv, oacc[dt], 0, 0, 0);
      }
    }
    __builtin_amdgcn_s_setprio(0);

    // retire tile ks reads, then stage tile ks+1 from regs (write-late: the
    // vmcnt wait on the prefetch happens here, ~a full compute phase later)
    asm volatile("s_waitcnt lgkmcnt(0)" ::: "memory");
    __builtin_amdgcn_s_barrier();
    if (ks + 1 < nks) {
      *(u16x8*)&sK [kr][kc]      = kg0; *(u16x8*)&sK [kr][kc + 8]  = kg1;
      *(u16x8*)&sK [kr][kc + 16] = kg2; *(u16x8*)&sK [kr][kc + 24] = kg3;
      *(u16x8*)&sVt[vr][vc]      = vg0; *(u16x8*)&sVt[vr][vc + 8]  = vg1;
      *(u16x8*)&sVt[vr][vc + 16] = vg2; *(u16x8*)&sVt[vr][vc + 24] = vg3;
    }
  }

  // epilogue: O /= l, write bf16 [token][h*64 + d]
  #pragma unroll
  for (int r = 0; r < 4; ++r) {
    const float il = 1.0f / __shfl(l_s, fq*4 + r, 64);
    const int q = t0 + w*16 + fq*4 + r;
    #pragma unroll
    for (int dt = 0; dt < 4; ++dt)
      out[(size_t)(b*T_ + q)*C_ + h*HS_ + dt*16 + l15] = f2bf(oacc[dt][r] * il);
  }
}

extern "C" void kernel_launch(void* const* d_in, const int* in_sizes, int n_in,
                              void* d_out, int out_size, void* d_ws, size_t ws_size,
                              hipStream_t stream)
{
  const float* x   = (const float*)d_in[0];
  const float* Wq  = (const float*)d_in[1];
  const float* Wk  = (const float*)d_in[2];
  const float* Wv  = (const float*)d_in[3];
  const float* Wo  = (const float*)d_in[4];
  const float* bo  = (const float*)d_in[5];
  const float* W1  = (const float*)d_in[6];
  const float* b1  = (const float*)d_in[7];
  const float* W2  = (const float*)d_in[8];
  const float* b2  = (const float*)d_in[9];
  const float* g1  = (const float*)d_in[10];
  const float* be1 = (const float*)d_in[11];
  const float* g2  = (const float*)d_in[12];
  const float* be2 = (const float*)d_in[13];
  float* out = (float*)d_out;

  // Workspace (96 MB peak, liveness-based reuse):
  char* ws = (char*)d_ws;
  unsigned short* BtQKV = (unsigned short*)(ws + (size_t) 0*MB);  // 6MB
  unsigned short* BtWo  = (unsigned short*)(ws + (size_t) 6*MB);  // 2MB
  unsigned short* BtW1  = (unsigned short*)(ws + (size_t) 8*MB);  // 8MB
  unsigned short* BtW2  = (unsigned short*)(ws + (size_t)16*MB);  // 8MB
  unsigned short* lnb   = (unsigned short*)(ws + (size_t)24*MB);  // 8MB
  unsigned short* qkvb  = (unsigned short*)(ws + (size_t)32*MB);  // [4096][3072] 24MB
  unsigned short* vtb   = (unsigned short*)(ws + (size_t)56*MB);  // [32][64][2048] 8MB
  unsigned short* attnb = (unsigned short*)(ws + (size_t)64*MB);  // 8MB
  float*          x2    = (float*)         (ws + (size_t)32*MB);  // 16MB (qkv dead)
  unsigned short* hb    = (unsigned short*)(ws + (size_t)32*MB);  // 32MB (x2,vt dead)
  // split-K bf16 partials for W2: [4][4096][1024] bf16 = 32 MB (attnb dead).
  unsigned short* pk4   = (unsigned short*)(ws + (size_t)64*MB);  // 32MB

  dim3 blk(256);

  // Weight transposes (QKV fused into one dispatch: z = which*16 + head)
  transpose_cast_qkv<<<dim3(HS_/32, C_/32, 3*H_), blk, 0, stream>>>(Wq, Wk, Wv, BtQKV);
  transpose_cast<<<dim3(C_/32,  C_/32, 1),  blk, 0, stream>>>(Wo, BtWo, C_, C_);
  transpose_cast<<<dim3(4*C_/32,C_/32, 1),  blk, 0, stream>>>(W1, BtW1, C_, 4*C_);
  transpose_cast<<<dim3(C_/32,4*C_/32, 1),  blk, 0, stream>>>(W2, BtW2, 4*C_, C_);

  ln_kernel<<<dim3(N_ROWS), blk, 0, stream>>>(x, g1, be1, lnb);

  // Fused QKV GEMM -> bf16 [4096][3072]   (128^2 v4, 32x24 = 768 blocks, 3/CU)
  gemm128<false,false><<<dim3(N_ROWS/128, 3072/128, 1), blk, 0, stream>>>(
      lnb, BtQKV, nullptr, qkvb, N_ROWS, 3072, C_, C_);

  // V transpose -> vt[bh][d][t]
  v_transpose<<<dim3(T_/64, B_*H_), blk, 0, stream>>>(qkvb, vtb);

  // MFMA flash attention v4 -> bf16 attnb  (32 bh x 32 qt = 1024 blocks)
  attn_mfma<<<dim3(B_*H_, T_/64), blk, 0, stream>>>(qkvb, vtb, attnb);

  // Wo GEMM + bias + residual(ln1) -> fp32 x2   (128x64 2-phase, 512 blocks)
  gemm_bf16<64,false,false,true,true><<<dim3(N_ROWS/128, C_/64), blk, 0, stream>>>(
      attnb, BtWo, bo, lnb, x2, N_ROWS, C_, C_);

  // LN2
  ln_kernel<<<dim3(N_ROWS), blk, 0, stream>>>(x2, g2, be2, lnb);

  // W1 GEMM + bias + ReLU -> bf16 hb   (128^2 v4, 32x32 = 1024 blocks, 4/CU)
  gemm128<true,true><<<dim3(N_ROWS/128, 4*C_/128, 1), blk, 0, stream>>>(
      lnb, BtW1, b1, hb, N_ROWS, 4*C_, C_, C_);

  // W2 GEMM split-K=4 -> bf16 partials  (128^2 v4, 32x8x4 = 1024 blocks, 4/CU)
  gemm128<false,false><<<dim3(N_ROWS/128, C_/128, 4), blk, 0, stream>>>(
      hb, BtW2, nullptr, pk4, N_ROWS, C_, 4*C_, C_);

  // reduce: out = sum(partials) + b2 + residual(ln2)
  splitk_reduce<4><<<dim3((N_ROWS * C_) / (256 * 4)), blk, 0, stream>>>(
      pk4, b2, lnb, out);
}

// Round 9
// 337.021 us; speedup vs baseline: 1.0171x; 1.0171x over previous
//
#include <hip/hip_runtime.h>
#include <hip/hip_bf16.h>
#include <math.h>

#define B_ 2
#define T_ 2048
#define C_ 1024
#define H_ 16
#define HS_ 64
#define N_ROWS (B_*T_)   // 4096
#define MB (1024*1024)

typedef __attribute__((ext_vector_type(8))) short bf16x8;
typedef __attribute__((ext_vector_type(8))) unsigned short u16x8;
typedef __attribute__((ext_vector_type(4))) float floatx4;

static __device__ __forceinline__ unsigned short f2bf(float f) {
  union { float f; unsigned u; } v; v.f = f;
  unsigned r = v.u + 0x7fff + ((v.u >> 16) & 1);   // round-to-nearest-even
  return (unsigned short)(r >> 16);
}
static __device__ __forceinline__ float bf2f(unsigned short s) {
  union { unsigned u; float f; } v; v.u = ((unsigned)s) << 16;
  return v.f;
}

// ---------------- LayerNorm: one block per row, bf16 output ----------------
__global__ __launch_bounds__(256) void ln_kernel(
    const float* __restrict__ x, const float* __restrict__ g,
    const float* __restrict__ b, unsigned short* __restrict__ outb)
{
  const int row = blockIdx.x;
  const int tid = threadIdx.x;
  const float* xr = x + (size_t)row * C_;
  float4 xv = *reinterpret_cast<const float4*>(xr + tid * 4);
  float s  = xv.x + xv.y + xv.z + xv.w;
  float ss = xv.x*xv.x + xv.y*xv.y + xv.z*xv.z + xv.w*xv.w;
  #pragma unroll
  for (int off = 32; off > 0; off >>= 1) {
    s  += __shfl_down(s, off, 64);
    ss += __shfl_down(ss, off, 64);
  }
  __shared__ float rs[4], rss[4];
  __shared__ float smu, srstd;
  if ((tid & 63) == 0) { rs[tid >> 6] = s; rss[tid >> 6] = ss; }
  __syncthreads();
  if (tid == 0) {
    float S  = rs[0] + rs[1] + rs[2] + rs[3];
    float SS = rss[0] + rss[1] + rss[2] + rss[3];
    float mu  = S * (1.0f / C_);
    float var = SS * (1.0f / C_) - mu * mu;
    smu = mu; srstd = rsqrtf(var + 1e-5f);
  }
  __syncthreads();
  const float mu = smu, rstd = srstd;
  float4 gv = *reinterpret_cast<const float4*>(g + tid * 4);
  float4 bv = *reinterpret_cast<const float4*>(b + tid * 4);
  union { unsigned long long ll; unsigned short s[4]; } o;
  o.s[0] = f2bf((xv.x - mu) * rstd * gv.x + bv.x);
  o.s[1] = f2bf((xv.y - mu) * rstd * gv.y + bv.y);
  o.s[2] = f2bf((xv.z - mu) * rstd * gv.z + bv.z);
  o.s[3] = f2bf((xv.w - mu) * rstd * gv.w + bv.w);
  *reinterpret_cast<unsigned long long*>(outb + (size_t)row * C_ + tid * 4) = o.ll;
}

// ---------------- Transpose + cast: fp32 [R][Cc] -> bf16 [Cc][R], batched ---
__global__ __launch_bounds__(256) void transpose_cast(
    const float* __restrict__ in, unsigned short* __restrict__ out, int R, int Cc)
{
  __shared__ float tile[32][33];
  const int bz = blockIdx.z;
  in  += (size_t)bz * R * Cc;
  out += (size_t)bz * R * Cc;
  const int tx = threadIdx.x & 31;
  const int ty = threadIdx.x >> 5;    // 0..7
  const int c0 = blockIdx.x * 32, r0 = blockIdx.y * 32;
  #pragma unroll
  for (int j = 0; j < 4; ++j)
    tile[ty + j*8][tx] = in[(size_t)(r0 + ty + j*8) * Cc + c0 + tx];
  __syncthreads();
  #pragma unroll
  for (int j = 0; j < 4; ++j)
    out[(size_t)(c0 + ty + j*8) * R + r0 + tx] = f2bf(tile[tx][ty + j*8]);
}

// Fused QKV weight transpose: z in [0,48) -> which = z/16, head = z%16.
__global__ __launch_bounds__(256) void transpose_cast_qkv(
    const float* __restrict__ Wq, const float* __restrict__ Wk,
    const float* __restrict__ Wv, unsigned short* __restrict__ out)
{
  __shared__ float tile[32][33];
  const int z = blockIdx.z;
  const int which = z >> 4, h = z & 15;
  const float* in = (which == 0 ? Wq : which == 1 ? Wk : Wv) + (size_t)h * C_ * HS_;
  unsigned short* dst = out + (size_t)z * C_ * HS_;
  const int tx = threadIdx.x & 31;
  const int ty = threadIdx.x >> 5;
  const int c0 = blockIdx.x * 32, r0 = blockIdx.y * 32;
  #pragma unroll
  for (int j = 0; j < 4; ++j)
    tile[ty + j*8][tx] = in[(size_t)(r0 + ty + j*8) * HS_ + c0 + tx];
  __syncthreads();
  #pragma unroll
  for (int j = 0; j < 4; ++j)
    dst[(size_t)(c0 + ty + j*8) * C_ + r0 + tx] = f2bf(tile[tx][ty + j*8]);
}

// ========= 128x256 bf16 GEMM v4: 3-deep ring, counted vmcnt(3) =========
// R8 post-mortem: 4-blocks/CU (128^2) REGRESSED (occupancy stuck ~33%,
// worse reuse) -> TLP axis exhausted. Remaining stall identified in the
// R7 loop: vmcnt(0) at iteration bottom waits for loads issued at the
// SAME iteration's top (~300cy elapsed vs 300-500cy L2 latency) -> each
// wave exposes 100-300cy per K-half. v4 keeps R7's proven shape
// (BM=128 BN=256, 8 waves 2Mx4N, 2 blocks/CU) and deepens the ring to 3
// (72KB LDS): STAGE(q+2) at top, vmcnt(3) at bottom waits for stage(q+1)
// issued one FULL iteration earlier (~700cy) -> latency fully covered,
// counted vmcnt never 0 mid-loop (T4 proper; tail drains 3->0).
// Write-safety: STAGE(q+2) overwrites slot (q-1)%3; its readers finished
// before iter (q-1)'s closing barrier (ds_reads retire before their
// consuming MFMAs). Swizzle/staging algebra unchanged (0 conflicts).
template<bool RELU, bool HASB>
__global__ __launch_bounds__(512, 4) void gemm256(
    const unsigned short* __restrict__ A,   // [M][Kfull] bf16
    const unsigned short* __restrict__ Bt,  // [N][Kfull] bf16
    const float* __restrict__ bias,         // [N] fp32 (HASB)
    unsigned short* __restrict__ Cout,      // [z][M][N] bf16
    int M, int N, int Kfull, int Kh)
{
  __shared__ __align__(16) unsigned short Asl[3 * 4096];  // 3 x [128][32] 24KB
  __shared__ __align__(16) unsigned short Bsl[3 * 8192];  // 3 x [256][32] 48KB
  const int tid = threadIdx.x;
  const int w = tid >> 6, l = tid & 63;
  const int wm = w & 1, wn = w >> 1;          // 2M x 4N wave grid, 64x64/wave
  const int fr = l & 15, fq = l >> 4;
  const int m0 = blockIdx.x * 128, n0 = blockIdx.y * 256;
  const int z = blockIdx.z;

  const unsigned short* Aw = A  + (size_t)m0 * Kfull + (size_t)z * Kh;
  const unsigned short* Bw = Bt + (size_t)n0 * Kfull + (size_t)z * Kh;
  unsigned short* Cw = Cout + (size_t)z * M * N;

  // Staging (swizzled, R5/R7-verified): region[row][slot], slot holds
  // K-group g = (slot - (row>>1)) & 3; linear LDS dest (wave base +
  // lane*16B), per-lane pre-swizzled global K-group g.
  const int g    = ((l & 3) - ((l >> 3) & 3)) & 3;
  const int srow = w * 16 + (l >> 2);
  const unsigned short* ga  = Aw + (size_t)srow * Kfull + g * 8;   // 128 rows: 1 load
  const unsigned short* gb0 = Bw + (size_t)srow * Kfull + g * 8;   // 256 rows: 2 loads
  const unsigned short* gb1 = gb0 + (size_t)128 * Kfull;
  unsigned short* da0 = Asl + w * 512;
  unsigned short* db0 = Bsl + w * 512;

  const int Qmax = (Kh >> 5) - 1;   // K-halves - 1 (31 for Kh=1024)

  auto STAGE = [&](int q, int slot) {
    unsigned short* da = da0 + slot * 4096;
    unsigned short* db = db0 + slot * 8192;
    __builtin_amdgcn_global_load_lds(
        (const __attribute__((address_space(1))) void*)(ga + q * 32),
        (__attribute__((address_space(3))) void*)da, 16, 0, 0);
    __builtin_amdgcn_global_load_lds(
        (const __attribute__((address_space(1))) void*)(gb0 + q * 32),
        (__attribute__((address_space(3))) void*)db, 16, 0, 0);
    __builtin_amdgcn_global_load_lds(
        (const __attribute__((address_space(1))) void*)(gb1 + q * 32),
        (__attribute__((address_space(3))) void*)(db + 4096), 16, 0, 0);
  };

  // Fragment read offsets: slot = (fq + (row>>1)) & 3; row-base terms
  // (wm*64, wn*64, mf*16, nf*16) are 0 mod 8 -> only fr affects rotation.
  const int slot8 = ((fq + (fr >> 1)) & 3) * 8;
  const int aoff = (wm * 64 + fr) * 32 + slot8;   // + mf*512
  const int boff = (wn * 64 + fr) * 32 + slot8;   // + nf*512

  floatx4 acc[4][4] = {};

  // Prologue: stage K-halves 0,1; publish slot 0 (wait oldest 3 of 6).
  STAGE(0, 0);
  STAGE(1, 1);
  asm volatile("s_waitcnt vmcnt(3)" ::: "memory");
  __builtin_amdgcn_s_barrier();

  int s = 0;                         // ring slot of K-half q
  #pragma unroll 1
  for (int q = 0; q <= Qmax; ++q) {
    int s2 = s + 2; if (s2 >= 3) s2 -= 3;       // slot for q+2 (= slot q-1)
    if (q + 2 <= Qmax) STAGE(q + 2, s2);
    const unsigned short* Ar = Asl + s * 4096;
    const unsigned short* Br = Bsl + s * 8192;
    bf16x8 af[4], bfr[4];
    #pragma unroll
    for (int mf = 0; mf < 4; ++mf)
      af[mf]  = *(const bf16x8*)(Ar + aoff + mf * 512);
    #pragma unroll
    for (int nf = 0; nf < 4; ++nf)
      bfr[nf] = *(const bf16x8*)(Br + boff + nf * 512);
    __builtin_amdgcn_s_setprio(1);
    #pragma unroll
    for (int mf = 0; mf < 4; ++mf)
      #pragma unroll
      for (int nf = 0; nf < 4; ++nf)
        acc[mf][nf] = __builtin_amdgcn_mfma_f32_16x16x32_bf16(
            af[mf], bfr[nf], acc[mf][nf], 0, 0, 0);
    __builtin_amdgcn_s_setprio(0);
    // publish slot of q+1: its loads were issued at the TOP of iter q-1
    // (or prologue) -> ~1.7 iterations in flight; counted wait, never 0
    // until the tail.
    if (q + 2 <= Qmax)      { asm volatile("s_waitcnt vmcnt(3)" ::: "memory"); }
    else if (q + 1 <= Qmax) { asm volatile("s_waitcnt vmcnt(0)" ::: "memory"); }
    if (q < Qmax) __builtin_amdgcn_s_barrier();
    if (++s == 3) s = 0;
  }

  // Epilogue: bias / relu / bf16 store.
  #pragma unroll
  for (int nf = 0; nf < 4; ++nf) {
    const int col = n0 + wn * 64 + nf * 16 + fr;
    const float bv = HASB ? bias[col] : 0.0f;
    #pragma unroll
    for (int mf = 0; mf < 4; ++mf) {
      #pragma unroll
      for (int r = 0; r < 4; ++r) {
        const int row = m0 + wm * 64 + mf * 16 + fq * 4 + r;
        float v = acc[mf][nf][r] + bv;
        if (RELU) v = v > 0.0f ? v : 0.0f;
        Cw[(size_t)row * N + col] = f2bf(v);
      }
    }
  }
}

// ------------- bf16 MFMA GEMM (128^2 2-phase, R4-proven) — Wo only ---------
template<int TNB, bool OUTBF16, bool RELU, bool HASB, bool HASRES>
__global__ __launch_bounds__(256) void gemm_bf16(
    const unsigned short* __restrict__ A,   // [M][K] bf16
    const unsigned short* __restrict__ Bt,  // [N][K] bf16
    const float* __restrict__ bias,         // [N] fp32
    const unsigned short* __restrict__ res, // [M][N] bf16
    void* __restrict__ Cout,                // [M][N] fp32 or bf16
    int M, int N, int K)
{
  constexpr int NT = TNB / 32;              // B-tiles per wave: 4 or 2
  constexpr int WN = TNB / 2;               // wave n-extent: 64 or 32
  constexpr int LOADS = 4 + 2 * (TNB / 64); // gload_lds per thread per K-tile
  __shared__ unsigned short As[2][2][128 * 32];
  __shared__ unsigned short Bs[2][2][TNB * 32];
  const int tid  = threadIdx.x;
  const int lane = tid & 63;
  const int wave = tid >> 6;
  const int wm = wave & 1, wn = wave >> 1;
  const int m0 = blockIdx.x * 128, n0 = blockIdx.y * TNB;

  const int lrow = lane >> 2;
  const int lcol = (lane & 3) * 8;
  const int fr = lane & 15;
  const int fq = lane >> 4;

  floatx4 acc[4][NT] = {};

  const unsigned short* Aw = A  + (size_t)m0 * K;
  const unsigned short* Bw = Bt + (size_t)n0 * K;

  auto STAGE = [&](int bb, int k0) {
    #pragma unroll
    for (int half = 0; half < 2; ++half) {
      #pragma unroll
      for (int i = 0; i < 2; ++i) {
        const int rbase = i * 64 + wave * 16;
        const unsigned short* gp =
            Aw + (size_t)(rbase + lrow) * K + k0 + half * 32 + lcol;
        __builtin_amdgcn_global_load_lds(
            (const __attribute__((address_space(1))) void*)gp,
            (__attribute__((address_space(3))) void*)(As[bb][half] + rbase * 32),
            16, 0, 0);
      }
      #pragma unroll
      for (int i = 0; i < TNB / 64; ++i) {
        const int rbase = i * 64 + wave * 16;
        const unsigned short* gp =
            Bw + (size_t)(rbase + lrow) * K + k0 + half * 32 + lcol;
        __builtin_amdgcn_global_load_lds(
            (const __attribute__((address_space(1))) void*)gp,
            (__attribute__((address_space(3))) void*)(Bs[bb][half] + rbase * 32),
            16, 0, 0);
      }
    }
  };

  auto COMPUTE = [&](int bb) {
    #pragma unroll
    for (int half = 0; half < 2; ++half) {
      bf16x8 af[4], bfr[NT];
      #pragma unroll
      for (int t = 0; t < 4; ++t)
        af[t]  = *reinterpret_cast<const bf16x8*>(
            As[bb][half] + (wm*64 + t*16 + fr)*32 + fq*8);
      #pragma unroll
      for (int t = 0; t < NT; ++t)
        bfr[t] = *reinterpret_cast<const bf16x8*>(
            Bs[bb][half] + (wn*WN + t*16 + fr)*32 + fq*8);
      #pragma unroll
      for (int mt = 0; mt < 4; ++mt)
        #pragma unroll
        for (int nt = 0; nt < NT; ++nt)
          acc[mt][nt] = __builtin_amdgcn_mfma_f32_16x16x32_bf16(
              af[mt], bfr[nt], acc[mt][nt], 0, 0, 0);
    }
  };

  STAGE(0, 0);
  int bb = 0;
  for (int k0 = 64; k0 < K; k0 += 64) {
    STAGE(bb ^ 1, k0);                       // next tile: stays in flight
    asm volatile("s_waitcnt vmcnt(%0)" :: "n"(LOADS) : "memory");
    __builtin_amdgcn_s_barrier();            // tile bb fully in LDS, all waves
    COMPUTE(bb);
    __builtin_amdgcn_s_barrier();            // all waves done reading bb
    bb ^= 1;
  }
  asm volatile("s_waitcnt vmcnt(0)" ::: "memory");
  __builtin_amdgcn_s_barrier();
  COMPUTE(bb);

  #pragma unroll
  for (int nt = 0; nt < NT; ++nt) {
    const int col = n0 + wn*WN + nt*16 + fr;
    const float bv = HASB ? bias[col] : 0.0f;
    #pragma unroll
    for (int mt = 0; mt < 4; ++mt) {
      #pragma unroll
      for (int r = 0; r < 4; ++r) {
        const int row = m0 + wm*64 + mt*16 + fq*4 + r;
        float v = acc[mt][nt][r] + bv;
        if (RELU) v = v > 0.0f ? v : 0.0f;
        if (HASRES) v += bf2f(res[(size_t)row * N + col]);
        if (OUTBF16) ((unsigned short*)Cout)[(size_t)row * N + col] = f2bf(v);
        else         ((float*)Cout)[(size_t)row * N + col] = v;
      }
    }
  }
}

// -------- split-K reduce: out = sum_z p[z] + bias + res (all bf16 in) ------
template<int SPLITS>
__global__ __launch_bounds__(256) void splitk_reduce(
    const unsigned short* __restrict__ p,   // [SPLITS][M*N] bf16
    const float* __restrict__ bias, const unsigned short* __restrict__ res,
    float* __restrict__ out)
{
  const size_t i = ((size_t)blockIdx.x * 256 + threadIdx.x) * 4;
  const size_t MN = (size_t)N_ROWS * C_;
  float4 bv = *reinterpret_cast<const float4*>(bias + (i & (size_t)(C_ - 1)));
  float acc[4] = {bv.x, bv.y, bv.z, bv.w};
  {
    const unsigned short* rp = res + i;
    #pragma unroll
    for (int j = 0; j < 4; ++j) acc[j] += bf2f(rp[j]);
  }
  #pragma unroll
  for (int z = 0; z < SPLITS; ++z) {
    const unsigned short* pp = p + (size_t)z * MN + i;
    #pragma unroll
    for (int j = 0; j < 4; ++j) acc[j] += bf2f(pp[j]);
  }
  float4 o; o.x = acc[0]; o.y = acc[1]; o.z = acc[2]; o.w = acc[3];
  *reinterpret_cast<float4*>(out + i) = o;
}

// ---------------- V transpose: qkv V-part -> vt[bh][64 d][2048 t] bf16 -----
__global__ __launch_bounds__(256) void v_transpose(
    const unsigned short* __restrict__ qkv, unsigned short* __restrict__ vt)
{
  __shared__ __align__(16) unsigned short sT[64][72];
  const int st = blockIdx.x;        // s-tile of 64
  const int bh = blockIdx.y;
  const int b = bh >> 4, h = bh & 15;
  const int t = threadIdx.x;
  const int r = t >> 2, c0 = (t & 3) * 16;
  const unsigned short* src =
      qkv + (size_t)(b * T_ + st * 64 + r) * 3072 + 2048 + h * 64 + c0;
  *(u16x8*)&sT[r][c0]     = *(const u16x8*)src;
  *(u16x8*)&sT[r][c0 + 8] = *(const u16x8*)(src + 8);
  __syncthreads();
  const int d = t >> 2, sc = (t & 3) * 16;
  unsigned short v[16];
  #pragma unroll
  for (int j = 0; j < 16; ++j) v[j] = sT[sc + j][d];
  unsigned short* dst = vt + ((size_t)bh * 64 + d) * (size_t)T_ + st * 64 + sc;
  *(uint4*)dst       = *(uint4*)&v[0];
  *(uint4*)(dst + 8) = *(uint4*)&v[8];
}

// ---------------- MFMA flash attention v4 (unchanged from R2) --------------
__global__ __launch_bounds__(256, 3) void attn_mfma(
    const unsigned short* __restrict__ qkv,
    const unsigned short* __restrict__ vt,
    unsigned short* __restrict__ out)
{
  const int bh = blockIdx.x;
  const int qt = (int)(gridDim.y - 1) - (int)blockIdx.y;  // long blocks first
  const int b = bh >> 4, h = bh & 15;
  const int tid = threadIdx.x;
  const int w = tid >> 6;
  const int lane = tid & 63;
  const int l15 = lane & 15, fq = lane >> 4;
  const int t0 = qt * 64;
  const int q_row = t0 + w * 16 + l15;   // this lane's q column

  __shared__ __align__(16) unsigned short sK [128][72];   // [s][d]
  __shared__ __align__(16) unsigned short sVt[64][136];   // [d][s]
  __shared__ __align__(16) unsigned short sP [64][136];   // [q][s], wave-private rows

  const float c1 = 1.4426950408889634f / 32.0f;   // log2(e) * C^-0.5

  // Q fragment (dual-use A/B layout): Q[q_row][d = c*32 + fq*8 + j]
  bf16x8 aq[2];
  {
    const unsigned short* qp = qkv + (size_t)(b*T_ + q_row)*3072 + h*HS_ + fq*8;
    aq[0] = *(const bf16x8*)qp;
    aq[1] = *(const bf16x8*)(qp + 32);
  }

  const int nks = (qt >> 1) + 1;          // 128-wide K/V tiles

  // staging lane coords (K: 128 rows x 64 d; Vt: 64 rows x 128 s)
  const int kr = tid >> 1, kc = (tid & 1) * 32;
  const int vr = tid >> 2, vc = (tid & 3) * 32;
  const unsigned short* kp0 =
      qkv + (size_t)(b*T_ + kr)*3072 + C_ + h*HS_ + kc;
  const unsigned short* vp0 =
      vt + ((size_t)bh*64 + vr)*(size_t)T_ + vc;

  // prologue: load tile 0 and stage it (latency exposed once per block)
  u16x8 kg0, kg1, kg2, kg3, vg0, vg1, vg2, vg3;
  kg0 = *(const u16x8*)kp0;      kg1 = *(const u16x8*)(kp0 + 8);
  kg2 = *(const u16x8*)(kp0+16); kg3 = *(const u16x8*)(kp0 + 24);
  vg0 = *(const u16x8*)vp0;      vg1 = *(const u16x8*)(vp0 + 8);
  vg2 = *(const u16x8*)(vp0+16); vg3 = *(const u16x8*)(vp0 + 24);
  *(u16x8*)&sK [kr][kc]      = kg0; *(u16x8*)&sK [kr][kc + 8]  = kg1;
  *(u16x8*)&sK [kr][kc + 16] = kg2; *(u16x8*)&sK [kr][kc + 24] = kg3;
  *(u16x8*)&sVt[vr][vc]      = vg0; *(u16x8*)&sVt[vr][vc + 8]  = vg1;
  *(u16x8*)&sVt[vr][vc + 16] = vg2; *(u16x8*)&sVt[vr][vc + 24] = vg3;

  floatx4 oacc[4] = {};   // [dt]; C/D: col d = dt*16+l15, row q-local = fq*4+r
  float m_s = -3.0e38f, l_s = 0.0f;

  #pragma unroll 1
  for (int ks = 0; ks < nks; ++ks) {
    // publish tile ks (staged at prologue / bottom of previous iteration)
    asm volatile("s_waitcnt lgkmcnt(0)" ::: "memory");
    __builtin_amdgcn_s_barrier();

    // T14: issue tile ks+1 global loads now; they complete under the compute
    if (ks + 1 < nks) {
      const unsigned short* kp = kp0 + (size_t)(ks + 1) * (128 * 3072);
      kg0 = *(const u16x8*)kp;        kg1 = *(const u16x8*)(kp + 8);
      kg2 = *(const u16x8*)(kp + 16); kg3 = *(const u16x8*)(kp + 24);
      const unsigned short* vp = vp0 + (ks + 1) * 128;
      vg0 = *(const u16x8*)vp;        vg1 = *(const u16x8*)(vp + 8);
      vg2 = *(const u16x8*)(vp + 16); vg3 = *(const u16x8*)(vp + 24);
    }

    // S^T = K-tile · Q^T : D[m = s-local = st*16+fq*4+r][n = q-local = l15]
    floatx4 stacc[8] = {};
    __builtin_amdgcn_s_setprio(1);
    #pragma unroll
    for (int st = 0; st < 8; ++st) {
      bf16x8 ka = *(const bf16x8*)&sK[st*16 + l15][fq*8];
      bf16x8 kb = *(const bf16x8*)&sK[st*16 + l15][32 + fq*8];
      stacc[st] = __builtin_amdgcn_mfma_f32_16x16x32_bf16(ka, aq[0], stacc[st], 0, 0, 0);
      stacc[st] = __builtin_amdgcn_mfma_f32_16x16x32_bf16(kb, aq[1], stacc[st], 0, 0, 0);
    }
    __builtin_amdgcn_s_setprio(0);

    if (ks == nks - 1) {   // diagonal tile: mask s > q
      const int sbase = ks*128 + fq*4;
      #pragma unroll
      for (int st = 0; st < 8; ++st)
        #pragma unroll
        for (int r = 0; r < 4; ++r)
          if (sbase + st*16 + r > q_row) stacc[st][r] = -3.0e38f;
    }

    // online softmax over s for this lane's q: in-lane 32 + 2 shfl_xor
    float mx = -3.0e38f;
    #pragma unroll
    for (int st = 0; st < 8; ++st)
      #pragma unroll
      for (int r = 0; r < 4; ++r) mx = fmaxf(mx, stacc[st][r]);
    mx = fmaxf(mx, __shfl_xor(mx, 16, 64));
    mx = fmaxf(mx, __shfl_xor(mx, 32, 64));

    float mnew;
    if (__all((mx - m_s) * c1 <= 8.0f)) {
      mnew = m_s;                       // defer: keep old max, no rescale
    } else {
      mnew = fmaxf(m_s, mx);
      const float alpha = __builtin_amdgcn_exp2f((m_s - mnew) * c1);
      #pragma unroll
      for (int r = 0; r < 4; ++r) {
        const float ar = __shfl(alpha, fq*4 + r, 64);
        #pragma unroll
        for (int dt = 0; dt < 4; ++dt) oacc[dt][r] *= ar;
      }
      l_s *= alpha;
      m_s = mnew;
    }

    const float mc = mnew * c1;
    float sum = 0.0f;
    #pragma unroll
    for (int st = 0; st < 8; ++st) {
      unsigned pu[4];
      #pragma unroll
      for (int r = 0; r < 4; ++r) {
        const float p = __builtin_amdgcn_exp2f(stacc[st][r] * c1 - mc);
        sum += p;
        union { float f; unsigned u; } cv; cv.f = p;
        pu[r] = cv.u + 0x8000u;              // round-half-up to bf16
      }
      const unsigned lo = __builtin_amdgcn_perm(pu[1], pu[0], 0x07060302u);
      const unsigned hi = __builtin_amdgcn_perm(pu[3], pu[2], 0x07060302u);
      // P[q][s]: row = wave-private q, col = 4 consecutive s
      *(unsigned long long*)&sP[w*16 + l15][st*16 + fq*4] =
          ((unsigned long long)hi << 32) | lo;
    }
    sum += __shfl_xor(sum, 16, 64);
    sum += __shfl_xor(sum, 32, 64);
    l_s += sum;

    // PV: O[q][d] += P[q][s] · V[s][d]   (sP rows are wave-private: no barrier)
    __builtin_amdgcn_s_setprio(1);
    #pragma unroll
    for (int c = 0; c < 4; ++c) {
      bf16x8 ap = *(const bf16x8*)&sP[w*16 + l15][c*32 + fq*8];
      #pragma unroll
      for (int dt = 0; dt < 4; ++dt) {
        bf16x8 bv = *(const bf16x8*)&sVt[dt*16 + l15][c*32 + fq*8];
        oacc[dt] = __builtin_amdgcn_mfma_f32_16x16x32_bf16(ap, bv, oacc[dt], 0, 0, 0);
      }
    }
    __builtin_amdgcn_s_setprio(0);

    // retire tile ks reads, then stage tile ks+1 from regs (write-late: the
    // vmcnt wait on the prefetch happens here, ~a full compute phase later)
    asm volatile("s_waitcnt lgkmcnt(0)" ::: "memory");
    __builtin_amdgcn_s_barrier();
    if (ks + 1 < nks) {
      *(u16x8*)&sK [kr][kc]      = kg0; *(u16x8*)&sK [kr][kc + 8]  = kg1;
      *(u16x8*)&sK [kr][kc + 16] = kg2; *(u16x8*)&sK [kr][kc + 24] = kg3;
      *(u16x8*)&sVt[vr][vc]      = vg0; *(u16x8*)&sVt[vr][vc + 8]  = vg1;
      *(u16x8*)&sVt[vr][vc + 16] = vg2; *(u16x8*)&sVt[vr][vc + 24] = vg3;
    }
  }

  // epilogue: O /= l, write bf16 [token][h*64 + d]
  #pragma unroll
  for (int r = 0; r < 4; ++r) {
    const float il = 1.0f / __shfl(l_s, fq*4 + r, 64);
    const int q = t0 + w*16 + fq*4 + r;
    #pragma unroll
    for (int dt = 0; dt < 4; ++dt)
      out[(size_t)(b*T_ + q)*C_ + h*HS_ + dt*16 + l15] = f2bf(oacc[dt][r] * il);
  }
}

extern "C" void kernel_launch(void* const* d_in, const int* in_sizes, int n_in,
                              void* d_out, int out_size, void* d_ws, size_t ws_size,
                              hipStream_t stream)
{
  const float* x   = (const float*)d_in[0];
  const float* Wq  = (const float*)d_in[1];
  const float* Wk  = (const float*)d_in[2];
  const float* Wv  = (const float*)d_in[3];
  const float* Wo  = (const float*)d_in[4];
  const float* bo  = (const float*)d_in[5];
  const float* W1  = (const float*)d_in[6];
  const float* b1  = (const float*)d_in[7];
  const float* W2  = (const float*)d_in[8];
  const float* b2  = (const float*)d_in[9];
  const float* g1  = (const float*)d_in[10];
  const float* be1 = (const float*)d_in[11];
  const float* g2  = (const float*)d_in[12];
  const float* be2 = (const float*)d_in[13];
  float* out = (float*)d_out;

  // Workspace (96 MB peak, liveness-based reuse):
  char* ws = (char*)d_ws;
  unsigned short* BtQKV = (unsigned short*)(ws + (size_t) 0*MB);  // 6MB
  unsigned short* BtWo  = (unsigned short*)(ws + (size_t) 6*MB);  // 2MB
  unsigned short* BtW1  = (unsigned short*)(ws + (size_t) 8*MB);  // 8MB
  unsigned short* BtW2  = (unsigned short*)(ws + (size_t)16*MB);  // 8MB
  unsigned short* lnb   = (unsigned short*)(ws + (size_t)24*MB);  // 8MB
  unsigned short* qkvb  = (unsigned short*)(ws + (size_t)32*MB);  // [4096][3072] 24MB
  unsigned short* vtb   = (unsigned short*)(ws + (size_t)56*MB);  // [32][64][2048] 8MB
  unsigned short* attnb = (unsigned short*)(ws + (size_t)64*MB);  // 8MB
  float*          x2    = (float*)         (ws + (size_t)32*MB);  // 16MB (qkv dead)
  unsigned short* hb    = (unsigned short*)(ws + (size_t)32*MB);  // 32MB (x2,vt dead)
  // split-K bf16 partials for W2: [4][4096][1024] bf16 = 32 MB (attnb dead).
  unsigned short* pk4   = (unsigned short*)(ws + (size_t)64*MB);  // 32MB

  dim3 blk(256);
  dim3 blk512(512);

  // Weight transposes (QKV fused into one dispatch: z = which*16 + head)
  transpose_cast_qkv<<<dim3(HS_/32, C_/32, 3*H_), blk, 0, stream>>>(Wq, Wk, Wv, BtQKV);
  transpose_cast<<<dim3(C_/32,  C_/32, 1),  blk, 0, stream>>>(Wo, BtWo, C_, C_);
  transpose_cast<<<dim3(4*C_/32,C_/32, 1),  blk, 0, stream>>>(W1, BtW1, C_, 4*C_);
  transpose_cast<<<dim3(C_/32,4*C_/32, 1),  blk, 0, stream>>>(W2, BtW2, 4*C_, C_);

  ln_kernel<<<dim3(N_ROWS), blk, 0, stream>>>(x, g1, be1, lnb);

  // Fused QKV GEMM -> bf16 [4096][3072]   (128x256 v4, 32x12 = 384 blocks)
  gemm256<false,false><<<dim3(N_ROWS/128, 3072/256, 1), blk512, 0, stream>>>(
      lnb, BtQKV, nullptr, qkvb, N_ROWS, 3072, C_, C_);

  // V transpose -> vt[bh][d][t]
  v_transpose<<<dim3(T_/64, B_*H_), blk, 0, stream>>>(qkvb, vtb);

  // MFMA flash attention v4 -> bf16 attnb  (32 bh x 32 qt = 1024 blocks)
  attn_mfma<<<dim3(B_*H_, T_/64), blk, 0, stream>>>(qkvb, vtb, attnb);

  // Wo GEMM + bias + residual(ln1) -> fp32 x2   (128x64 2-phase, 512 blocks)
  gemm_bf16<64,false,false,true,true><<<dim3(N_ROWS/128, C_/64), blk, 0, stream>>>(
      attnb, BtWo, bo, lnb, x2, N_ROWS, C_, C_);

  // LN2
  ln_kernel<<<dim3(N_ROWS), blk, 0, stream>>>(x2, g2, be2, lnb);

  // W1 GEMM + bias + ReLU -> bf16 hb   (128x256 v4, 32x16 = 512 blocks, 2/CU)
  gemm256<true,true><<<dim3(N_ROWS/128, 4*C_/256, 1), blk512, 0, stream>>>(
      lnb, BtW1, b1, hb, N_ROWS, 4*C_, C_, C_);

  // W2 GEMM split-K=4 -> bf16 partials  (128x256 v4, 32x4x4 = 512 blocks, 2/CU)
  gemm256<false,false><<<dim3(N_ROWS/128, C_/256, 4), blk512, 0, stream>>>(
      hb, BtW2, nullptr, pk4, N_ROWS, C_, 4*C_, C_);

  // reduce: out = sum(partials) + b2 + residual(ln2)
  splitk_reduce<4><<<dim3((N_ROWS * C_) / (256 * 4)), blk, 0, stream>>>(
      pk4, b2, lnb, out);
}

// Round 10
// 326.603 us; speedup vs baseline: 1.0495x; 1.0319x over previous
//
#include <hip/hip_runtime.h>
#include <hip/hip_bf16.h>
#include <math.h>

#define B_ 2
#define T_ 2048
#define C_ 1024
#define H_ 16
#define HS_ 64
#define N_ROWS (B_*T_)   // 4096
#define MB (1024*1024)

typedef __attribute__((ext_vector_type(8))) short bf16x8;
typedef __attribute__((ext_vector_type(8))) unsigned short u16x8;
typedef __attribute__((ext_vector_type(4))) float floatx4;

static __device__ __forceinline__ unsigned short f2bf(float f) {
  union { float f; unsigned u; } v; v.f = f;
  unsigned r = v.u + 0x7fff + ((v.u >> 16) & 1);   // round-to-nearest-even
  return (unsigned short)(r >> 16);
}
static __device__ __forceinline__ float bf2f(unsigned short s) {
  union { unsigned u; float f; } v; v.u = ((unsigned)s) << 16;
  return v.f;
}

// ---------------- LayerNorm: one block per row, bf16 output ----------------
__global__ __launch_bounds__(256) void ln_kernel(
    const float* __restrict__ x, const float* __restrict__ g,
    const float* __restrict__ b, unsigned short* __restrict__ outb)
{
  const int row = blockIdx.x;
  const int tid = threadIdx.x;
  const float* xr = x + (size_t)row * C_;
  float4 xv = *reinterpret_cast<const float4*>(xr + tid * 4);
  float s  = xv.x + xv.y + xv.z + xv.w;
  float ss = xv.x*xv.x + xv.y*xv.y + xv.z*xv.z + xv.w*xv.w;
  #pragma unroll
  for (int off = 32; off > 0; off >>= 1) {
    s  += __shfl_down(s, off, 64);
    ss += __shfl_down(ss, off, 64);
  }
  __shared__ float rs[4], rss[4];
  __shared__ float smu, srstd;
  if ((tid & 63) == 0) { rs[tid >> 6] = s; rss[tid >> 6] = ss; }
  __syncthreads();
  if (tid == 0) {
    float S  = rs[0] + rs[1] + rs[2] + rs[3];
    float SS = rss[0] + rss[1] + rss[2] + rss[3];
    float mu  = S * (1.0f / C_);
    float var = SS * (1.0f / C_) - mu * mu;
    smu = mu; srstd = rsqrtf(var + 1e-5f);
  }
  __syncthreads();
  const float mu = smu, rstd = srstd;
  float4 gv = *reinterpret_cast<const float4*>(g + tid * 4);
  float4 bv = *reinterpret_cast<const float4*>(b + tid * 4);
  union { unsigned long long ll; unsigned short s[4]; } o;
  o.s[0] = f2bf((xv.x - mu) * rstd * gv.x + bv.x);
  o.s[1] = f2bf((xv.y - mu) * rstd * gv.y + bv.y);
  o.s[2] = f2bf((xv.z - mu) * rstd * gv.z + bv.z);
  o.s[3] = f2bf((xv.w - mu) * rstd * gv.w + bv.w);
  *reinterpret_cast<unsigned long long*>(outb + (size_t)row * C_ + tid * 4) = o.ll;
}

// ---------------- Transpose + cast: fp32 [R][Cc] -> bf16 [Cc][R], batched ---
__global__ __launch_bounds__(256) void transpose_cast(
    const float* __restrict__ in, unsigned short* __restrict__ out, int R, int Cc)
{
  __shared__ float tile[32][33];
  const int bz = blockIdx.z;
  in  += (size_t)bz * R * Cc;
  out += (size_t)bz * R * Cc;
  const int tx = threadIdx.x & 31;
  const int ty = threadIdx.x >> 5;    // 0..7
  const int c0 = blockIdx.x * 32, r0 = blockIdx.y * 32;
  #pragma unroll
  for (int j = 0; j < 4; ++j)
    tile[ty + j*8][tx] = in[(size_t)(r0 + ty + j*8) * Cc + c0 + tx];
  __syncthreads();
  #pragma unroll
  for (int j = 0; j < 4; ++j)
    out[(size_t)(c0 + ty + j*8) * R + r0 + tx] = f2bf(tile[tx][ty + j*8]);
}

// Fused QKV weight transpose: z in [0,48) -> which = z/16, head = z%16.
__global__ __launch_bounds__(256) void transpose_cast_qkv(
    const float* __restrict__ Wq, const float* __restrict__ Wk,
    const float* __restrict__ Wv, unsigned short* __restrict__ out)
{
  __shared__ float tile[32][33];
  const int z = blockIdx.z;
  const int which = z >> 4, h = z & 15;
  const float* in = (which == 0 ? Wq : which == 1 ? Wk : Wv) + (size_t)h * C_ * HS_;
  unsigned short* dst = out + (size_t)z * C_ * HS_;
  const int tx = threadIdx.x & 31;
  const int ty = threadIdx.x >> 5;
  const int c0 = blockIdx.x * 32, r0 = blockIdx.y * 32;
  #pragma unroll
  for (int j = 0; j < 4; ++j)
    tile[ty + j*8][tx] = in[(size_t)(r0 + ty + j*8) * HS_ + c0 + tx];
  __syncthreads();
  #pragma unroll
  for (int j = 0; j < 4; ++j)
    dst[(size_t)(c0 + ty + j*8) * C_ + r0 + tx] = f2bf(tile[tx][ty + j*8]);
}

// ========= 128x256 bf16 GEMM v3 (R7-proven BEST): 2 blocks/CU, dbuf =========
// R9 post-mortem: 3-deep ring + counted vmcnt(3) was null-to-negative
// (total 332.7 -> 337.0) -- another pipelining null on this structure.
// REVERTED to the R7 exact version (best measured: 332.7 us, W1/W2 >= 734 TF
// at 2 blocks/CU, 0 bank conflicts).
template<bool RELU, bool HASB>
__global__ __launch_bounds__(512, 4) void gemm256(
    const unsigned short* __restrict__ A,   // [M][Kfull] bf16
    const unsigned short* __restrict__ Bt,  // [N][Kfull] bf16
    const float* __restrict__ bias,         // [N] fp32 (HASB)
    unsigned short* __restrict__ Cout,      // [z][M][N] bf16
    int M, int N, int Kfull, int Kh)
{
  __shared__ __align__(16) unsigned short Asl[2 * 4096];  // 2 x [128][32]  8KB
  __shared__ __align__(16) unsigned short Bsl[2 * 8192];  // 2 x [256][32] 16KB
  const int tid = threadIdx.x;
  const int w = tid >> 6, l = tid & 63;
  const int wm = w & 1, wn = w >> 1;          // 2M x 4N wave grid, 64x64/wave
  const int fr = l & 15, fq = l >> 4;
  const int m0 = blockIdx.x * 128, n0 = blockIdx.y * 256;
  const int z = blockIdx.z;

  const unsigned short* Aw = A  + (size_t)m0 * Kfull + (size_t)z * Kh;
  const unsigned short* Bw = Bt + (size_t)n0 * Kfull + (size_t)z * Kh;
  unsigned short* Cw = Cout + (size_t)z * M * N;

  // Staging (swizzled, R5/R7-verified): region[row][slot], slot holds K-group
  // g = (slot - (row>>1)) & 3; linear LDS dest (wave base + lane*16B),
  // per-lane pre-swizzled global K-group g.
  const int g    = ((l & 3) - ((l >> 3) & 3)) & 3;
  const int srow = w * 16 + (l >> 2);
  const unsigned short* ga  = Aw + (size_t)srow * Kfull + g * 8;   // 128 rows: 1 load
  const unsigned short* gb0 = Bw + (size_t)srow * Kfull + g * 8;   // 256 rows: 2 loads
  const unsigned short* gb1 = gb0 + (size_t)128 * Kfull;
  unsigned short* da0 = Asl + w * 512;
  unsigned short* db0 = Bsl + w * 512;

  const int Qmax = (Kh >> 5) - 1;   // K-halves - 1 (31 for Kh=1024)

  auto STAGE = [&](int q) {
    unsigned short* da = da0 + (q & 1) * 4096;
    unsigned short* db = db0 + (q & 1) * 8192;
    __builtin_amdgcn_global_load_lds(
        (const __attribute__((address_space(1))) void*)(ga + q * 32),
        (__attribute__((address_space(3))) void*)da, 16, 0, 0);
    __builtin_amdgcn_global_load_lds(
        (const __attribute__((address_space(1))) void*)(gb0 + q * 32),
        (__attribute__((address_space(3))) void*)db, 16, 0, 0);
    __builtin_amdgcn_global_load_lds(
        (const __attribute__((address_space(1))) void*)(gb1 + q * 32),
        (__attribute__((address_space(3))) void*)(db + 4096), 16, 0, 0);
  };

  // Fragment read offsets: slot = (fq + (row>>1)) & 3; row-base terms
  // (wm*64, wn*64, mf*16, nf*16) are 0 mod 8 -> only fr affects rotation.
  const int slot8 = ((fq + (fr >> 1)) & 3) * 8;
  const int aoff = (wm * 64 + fr) * 32 + slot8;   // + mf*512
  const int boff = (wn * 64 + fr) * 32 + slot8;   // + nf*512

  floatx4 acc[4][4] = {};

  STAGE(0);
  asm volatile("s_waitcnt vmcnt(0)" ::: "memory");
  __builtin_amdgcn_s_barrier();

  #pragma unroll 1
  for (int q = 0; q <= Qmax; ++q) {
    if (q < Qmax) STAGE(q + 1);          // into region (q+1)&1 (not being read)
    const unsigned short* Ar = Asl + (q & 1) * 4096;
    const unsigned short* Br = Bsl + (q & 1) * 8192;
    bf16x8 af[4], bfr[4];
    #pragma unroll
    for (int mf = 0; mf < 4; ++mf)
      af[mf]  = *(const bf16x8*)(Ar + aoff + mf * 512);
    #pragma unroll
    for (int nf = 0; nf < 4; ++nf)
      bfr[nf] = *(const bf16x8*)(Br + boff + nf * 512);
    __builtin_amdgcn_s_setprio(1);
    #pragma unroll
    for (int mf = 0; mf < 4; ++mf)
      #pragma unroll
      for (int nf = 0; nf < 4; ++nf)
        acc[mf][nf] = __builtin_amdgcn_mfma_f32_16x16x32_bf16(
            af[mf], bfr[nf], acc[mf][nf], 0, 0, 0);
    __builtin_amdgcn_s_setprio(0);
    if (q < Qmax) { asm volatile("s_waitcnt vmcnt(0)" ::: "memory"); }
    __builtin_amdgcn_s_barrier();
    // barrier semantics: (a) frag reads completed (lgkmcnt before MFMA)
    // before any wave's next STAGE overwrites this region; (b) vmcnt(0)
    // before barrier -> region (q+1)&1 fully written before it's read.
  }

  // Epilogue: bias / relu / bf16 store.
  #pragma unroll
  for (int nf = 0; nf < 4; ++nf) {
    const int col = n0 + wn * 64 + nf * 16 + fr;
    const float bv = HASB ? bias[col] : 0.0f;
    #pragma unroll
    for (int mf = 0; mf < 4; ++mf) {
      #pragma unroll
      for (int r = 0; r < 4; ++r) {
        const int row = m0 + wm * 64 + mf * 16 + fq * 4 + r;
        float v = acc[mf][nf][r] + bv;
        if (RELU) v = v > 0.0f ? v : 0.0f;
        Cw[(size_t)row * N + col] = f2bf(v);
      }
    }
  }
}

// ------------- bf16 MFMA GEMM (128^2 2-phase, R4-proven) — Wo only ---------
template<int TNB, bool OUTBF16, bool RELU, bool HASB, bool HASRES>
__global__ __launch_bounds__(256) void gemm_bf16(
    const unsigned short* __restrict__ A,   // [M][K] bf16
    const unsigned short* __restrict__ Bt,  // [N][K] bf16
    const float* __restrict__ bias,         // [N] fp32
    const unsigned short* __restrict__ res, // [M][N] bf16
    void* __restrict__ Cout,                // [M][N] fp32 or bf16
    int M, int N, int K)
{
  constexpr int NT = TNB / 32;              // B-tiles per wave: 4 or 2
  constexpr int WN = TNB / 2;               // wave n-extent: 64 or 32
  constexpr int LOADS = 4 + 2 * (TNB / 64); // gload_lds per thread per K-tile
  __shared__ unsigned short As[2][2][128 * 32];
  __shared__ unsigned short Bs[2][2][TNB * 32];
  const int tid  = threadIdx.x;
  const int lane = tid & 63;
  const int wave = tid >> 6;
  const int wm = wave & 1, wn = wave >> 1;
  const int m0 = blockIdx.x * 128, n0 = blockIdx.y * TNB;

  const int lrow = lane >> 2;
  const int lcol = (lane & 3) * 8;
  const int fr = lane & 15;
  const int fq = lane >> 4;

  floatx4 acc[4][NT] = {};

  const unsigned short* Aw = A  + (size_t)m0 * K;
  const unsigned short* Bw = Bt + (size_t)n0 * K;

  auto STAGE = [&](int bb, int k0) {
    #pragma unroll
    for (int half = 0; half < 2; ++half) {
      #pragma unroll
      for (int i = 0; i < 2; ++i) {
        const int rbase = i * 64 + wave * 16;
        const unsigned short* gp =
            Aw + (size_t)(rbase + lrow) * K + k0 + half * 32 + lcol;
        __builtin_amdgcn_global_load_lds(
            (const __attribute__((address_space(1))) void*)gp,
            (__attribute__((address_space(3))) void*)(As[bb][half] + rbase * 32),
            16, 0, 0);
      }
      #pragma unroll
      for (int i = 0; i < TNB / 64; ++i) {
        const int rbase = i * 64 + wave * 16;
        const unsigned short* gp =
            Bw + (size_t)(rbase + lrow) * K + k0 + half * 32 + lcol;
        __builtin_amdgcn_global_load_lds(
            (const __attribute__((address_space(1))) void*)gp,
            (__attribute__((address_space(3))) void*)(Bs[bb][half] + rbase * 32),
            16, 0, 0);
      }
    }
  };

  auto COMPUTE = [&](int bb) {
    #pragma unroll
    for (int half = 0; half < 2; ++half) {
      bf16x8 af[4], bfr[NT];
      #pragma unroll
      for (int t = 0; t < 4; ++t)
        af[t]  = *reinterpret_cast<const bf16x8*>(
            As[bb][half] + (wm*64 + t*16 + fr)*32 + fq*8);
      #pragma unroll
      for (int t = 0; t < NT; ++t)
        bfr[t] = *reinterpret_cast<const bf16x8*>(
            Bs[bb][half] + (wn*WN + t*16 + fr)*32 + fq*8);
      #pragma unroll
      for (int mt = 0; mt < 4; ++mt)
        #pragma unroll
        for (int nt = 0; nt < NT; ++nt)
          acc[mt][nt] = __builtin_amdgcn_mfma_f32_16x16x32_bf16(
              af[mt], bfr[nt], acc[mt][nt], 0, 0, 0);
    }
  };

  STAGE(0, 0);
  int bb = 0;
  for (int k0 = 64; k0 < K; k0 += 64) {
    STAGE(bb ^ 1, k0);                       // next tile: stays in flight
    asm volatile("s_waitcnt vmcnt(%0)" :: "n"(LOADS) : "memory");
    __builtin_amdgcn_s_barrier();            // tile bb fully in LDS, all waves
    COMPUTE(bb);
    __builtin_amdgcn_s_barrier();            // all waves done reading bb
    bb ^= 1;
  }
  asm volatile("s_waitcnt vmcnt(0)" ::: "memory");
  __builtin_amdgcn_s_barrier();
  COMPUTE(bb);

  #pragma unroll
  for (int nt = 0; nt < NT; ++nt) {
    const int col = n0 + wn*WN + nt*16 + fr;
    const float bv = HASB ? bias[col] : 0.0f;
    #pragma unroll
    for (int mt = 0; mt < 4; ++mt) {
      #pragma unroll
      for (int r = 0; r < 4; ++r) {
        const int row = m0 + wm*64 + mt*16 + fq*4 + r;
        float v = acc[mt][nt][r] + bv;
        if (RELU) v = v > 0.0f ? v : 0.0f;
        if (HASRES) v += bf2f(res[(size_t)row * N + col]);
        if (OUTBF16) ((unsigned short*)Cout)[(size_t)row * N + col] = f2bf(v);
        else         ((float*)Cout)[(size_t)row * N + col] = v;
      }
    }
  }
}

// -------- split-K reduce: out = sum_z p[z] + bias + res (all bf16 in) ------
template<int SPLITS>
__global__ __launch_bounds__(256) void splitk_reduce(
    const unsigned short* __restrict__ p,   // [SPLITS][M*N] bf16
    const float* __restrict__ bias, const unsigned short* __restrict__ res,
    float* __restrict__ out)
{
  const size_t i = ((size_t)blockIdx.x * 256 + threadIdx.x) * 4;
  const size_t MN = (size_t)N_ROWS * C_;
  float4 bv = *reinterpret_cast<const float4*>(bias + (i & (size_t)(C_ - 1)));
  float acc[4] = {bv.x, bv.y, bv.z, bv.w};
  {
    const unsigned short* rp = res + i;
    #pragma unroll
    for (int j = 0; j < 4; ++j) acc[j] += bf2f(rp[j]);
  }
  #pragma unroll
  for (int z = 0; z < SPLITS; ++z) {
    const unsigned short* pp = p + (size_t)z * MN + i;
    #pragma unroll
    for (int j = 0; j < 4; ++j) acc[j] += bf2f(pp[j]);
  }
  float4 o; o.x = acc[0]; o.y = acc[1]; o.z = acc[2]; o.w = acc[3];
  *reinterpret_cast<float4*>(out + i) = o;
}

// ---------------- V transpose: qkv V-part -> vt[bh][64 d][2048 t] bf16 -----
__global__ __launch_bounds__(256) void v_transpose(
    const unsigned short* __restrict__ qkv, unsigned short* __restrict__ vt)
{
  __shared__ __align__(16) unsigned short sT[64][72];
  const int st = blockIdx.x;        // s-tile of 64
  const int bh = blockIdx.y;
  const int b = bh >> 4, h = bh & 15;
  const int t = threadIdx.x;
  const int r = t >> 2, c0 = (t & 3) * 16;
  const unsigned short* src =
      qkv + (size_t)(b * T_ + st * 64 + r) * 3072 + 2048 + h * 64 + c0;
  *(u16x8*)&sT[r][c0]     = *(const u16x8*)src;
  *(u16x8*)&sT[r][c0 + 8] = *(const u16x8*)(src + 8);
  __syncthreads();
  const int d = t >> 2, sc = (t & 3) * 16;
  unsigned short v[16];
  #pragma unroll
  for (int j = 0; j < 16; ++j) v[j] = sT[sc + j][d];
  unsigned short* dst = vt + ((size_t)bh * 64 + d) * (size_t)T_ + st * 64 + sc;
  *(uint4*)dst       = *(uint4*)&v[0];
  *(uint4*)(dst + 8) = *(uint4*)&v[8];
}

// ---------------- MFMA flash attention v5 ----------------
// R9 post-mortem: attn is the top kernel (48.4us, MfmaUtil 13.5, VALU 30,
// occ 23). Static bank analysis: all LDS accesses already sit on the same
// 8-lanes-per-16B-slot floor distribution as the GEMM's measured-zero
// pattern -> the 7.2M SQ_LDS_BANK_CONFLICT is counted-but-free 2-way
// aliasing (m136/m98), NOT the stall. The per-tile critical path holds 4
// ds_bpermute reductions (~60cy each) between QK^T and PV. v5 removes
// them from the common path:
//  - l_s becomes a PER-LANE partial (lanes own disjoint s-slices of their
//    q-row); cross-fq reduce moved to the epilogue (2 shfls once).
//  - defer-max check uses the per-lane partial max: __all() already spans
//    all 64 lanes = all s-slices. The full cross-lane max (2 shfls) moves
//    into the rescale branch, which fires ~once per block (thr = 177
//    S-units; first tile takes it and sets finite m_s).
// Exact math preserved: P <= 2^8, masked -3e38 lanes defer trivially and
// contribute p=0; m_s stays fq-uniform (only updated with reduced mx).
__global__ __launch_bounds__(256, 3) void attn_mfma(
    const unsigned short* __restrict__ qkv,
    const unsigned short* __restrict__ vt,
    unsigned short* __restrict__ out)
{
  const int bh = blockIdx.x;
  const int qt = (int)(gridDim.y - 1) - (int)blockIdx.y;  // long blocks first
  const int b = bh >> 4, h = bh & 15;
  const int tid = threadIdx.x;
  const int w = tid >> 6;
  const int lane = tid & 63;
  const int l15 = lane & 15, fq = lane >> 4;
  const int t0 = qt * 64;
  const int q_row = t0 + w * 16 + l15;   // this lane's q column

  __shared__ __align__(16) unsigned short sK [128][72];   // [s][d]
  __shared__ __align__(16) unsigned short sVt[64][136];   // [d][s]
  __shared__ __align__(16) unsigned short sP [64][136];   // [q][s], wave-private rows

  const float c1 = 1.4426950408889634f / 32.0f;   // log2(e) * C^-0.5

  // Q fragment (dual-use A/B layout): Q[q_row][d = c*32 + fq*8 + j]
  bf16x8 aq[2];
  {
    const unsigned short* qp = qkv + (size_t)(b*T_ + q_row)*3072 + h*HS_ + fq*8;
    aq[0] = *(const bf16x8*)qp;
    aq[1] = *(const bf16x8*)(qp + 32);
  }

  const int nks = (qt >> 1) + 1;          // 128-wide K/V tiles

  // staging lane coords (K: 128 rows x 64 d; Vt: 64 rows x 128 s)
  const int kr = tid >> 1, kc = (tid & 1) * 32;
  const int vr = tid >> 2, vc = (tid & 3) * 32;
  const unsigned short* kp0 =
      qkv + (size_t)(b*T_ + kr)*3072 + C_ + h*HS_ + kc;
  const unsigned short* vp0 =
      vt + ((size_t)bh*64 + vr)*(size_t)T_ + vc;

  // prologue: load tile 0 and stage it (latency exposed once per block)
  u16x8 kg0, kg1, kg2, kg3, vg0, vg1, vg2, vg3;
  kg0 = *(const u16x8*)kp0;      kg1 = *(const u16x8*)(kp0 + 8);
  kg2 = *(const u16x8*)(kp0+16); kg3 = *(const u16x8*)(kp0 + 24);
  vg0 = *(const u16x8*)vp0;      vg1 = *(const u16x8*)(vp0 + 8);
  vg2 = *(const u16x8*)(vp0+16); vg3 = *(const u16x8*)(vp0 + 24);
  *(u16x8*)&sK [kr][kc]      = kg0; *(u16x8*)&sK [kr][kc + 8]  = kg1;
  *(u16x8*)&sK [kr][kc + 16] = kg2; *(u16x8*)&sK [kr][kc + 24] = kg3;
  *(u16x8*)&sVt[vr][vc]      = vg0; *(u16x8*)&sVt[vr][vc + 8]  = vg1;
  *(u16x8*)&sVt[vr][vc + 16] = vg2; *(u16x8*)&sVt[vr][vc + 24] = vg3;

  floatx4 oacc[4] = {};   // [dt]; C/D: col d = dt*16+l15, row q-local = fq*4+r
  float m_s = -3.0e38f, l_s = 0.0f;   // l_s: PER-LANE partial (v5)

  #pragma unroll 1
  for (int ks = 0; ks < nks; ++ks) {
    // publish tile ks (staged at prologue / bottom of previous iteration)
    asm volatile("s_waitcnt lgkmcnt(0)" ::: "memory");
    __builtin_amdgcn_s_barrier();

    // T14: issue tile ks+1 global loads now; they complete under the compute
    if (ks + 1 < nks) {
      const unsigned short* kp = kp0 + (size_t)(ks + 1) * (128 * 3072);
      kg0 = *(const u16x8*)kp;        kg1 = *(const u16x8*)(kp + 8);
      kg2 = *(const u16x8*)(kp + 16); kg3 = *(const u16x8*)(kp + 24);
      const unsigned short* vp = vp0 + (ks + 1) * 128;
      vg0 = *(const u16x8*)vp;        vg1 = *(const u16x8*)(vp + 8);
      vg2 = *(const u16x8*)(vp + 16); vg3 = *(const u16x8*)(vp + 24);
    }

    // S^T = K-tile · Q^T : D[m = s-local = st*16+fq*4+r][n = q-local = l15]
    floatx4 stacc[8] = {};
    __builtin_amdgcn_s_setprio(1);
    #pragma unroll
    for (int st = 0; st < 8; ++st) {
      bf16x8 ka = *(const bf16x8*)&sK[st*16 + l15][fq*8];
      bf16x8 kb = *(const bf16x8*)&sK[st*16 + l15][32 + fq*8];
      stacc[st] = __builtin_amdgcn_mfma_f32_16x16x32_bf16(ka, aq[0], stacc[st], 0, 0, 0);
      stacc[st] = __builtin_amdgcn_mfma_f32_16x16x32_bf16(kb, aq[1], stacc[st], 0, 0, 0);
    }
    __builtin_amdgcn_s_setprio(0);

    if (ks == nks - 1) {   // diagonal tile: mask s > q
      const int sbase = ks*128 + fq*4;
      #pragma unroll
      for (int st = 0; st < 8; ++st)
        #pragma unroll
        for (int r = 0; r < 4; ++r)
          if (sbase + st*16 + r > q_row) stacc[st][r] = -3.0e38f;
    }

    // per-lane partial max; cross-lane reduce ONLY on the rare rescale path
    float mx = -3.0e38f;
    #pragma unroll
    for (int st = 0; st < 8; ++st)
      #pragma unroll
      for (int r = 0; r < 4; ++r) mx = fmaxf(mx, stacc[st][r]);

    if (!__all((mx - m_s) * c1 <= 8.0f)) {
      mx = fmaxf(mx, __shfl_xor(mx, 16, 64));
      mx = fmaxf(mx, __shfl_xor(mx, 32, 64));
      const float mnew = fmaxf(m_s, mx);
      const float alpha = __builtin_amdgcn_exp2f((m_s - mnew) * c1);
      #pragma unroll
      for (int r = 0; r < 4; ++r) {
        const float ar = __shfl(alpha, fq*4 + r, 64);
        #pragma unroll
        for (int dt = 0; dt < 4; ++dt) oacc[dt][r] *= ar;
      }
      l_s *= alpha;        // per-lane partial scales by its own q's alpha
      m_s = mnew;
    }

    const float mc = m_s * c1;
    float sum = 0.0f;
    #pragma unroll
    for (int st = 0; st < 8; ++st) {
      unsigned pu[4];
      #pragma unroll
      for (int r = 0; r < 4; ++r) {
        const float p = __builtin_amdgcn_exp2f(stacc[st][r] * c1 - mc);
        sum += p;
        union { float f; unsigned u; } cv; cv.f = p;
        pu[r] = cv.u + 0x8000u;              // round-half-up to bf16
      }
      const unsigned lo = __builtin_amdgcn_perm(pu[1], pu[0], 0x07060302u);
      const unsigned hi = __builtin_amdgcn_perm(pu[3], pu[2], 0x07060302u);
      // P[q][s]: row = wave-private q, col = 4 consecutive s
      *(unsigned long long*)&sP[w*16 + l15][st*16 + fq*4] =
          ((unsigned long long)hi << 32) | lo;
    }
    l_s += sum;            // no per-tile cross-lane reduce (v5)

    // PV: O[q][d] += P[q][s] · V[s][d]   (sP rows are wave-private: no barrier)
    __builtin_amdgcn_s_setprio(1);
    #pragma unroll
    for (int c = 0; c < 4; ++c) {
      bf16x8 ap = *(const bf16x8*)&sP[w*16 + l15][c*32 + fq*8];
      #pragma unroll
      for (int dt = 0; dt < 4; ++dt) {
        bf16x8 bv = *(const bf16x8*)&sVt[dt*16 + l15][c*32 + fq*8];
        oacc[dt] = __builtin_amdgcn_mfma_f32_16x16x32_bf16(ap, bv, oacc[dt], 0, 0, 0);
      }
    }
    __builtin_amdgcn_s_setprio(0);

    // retire tile ks reads, then stage tile ks+1 from regs (write-late: the
    // vmcnt wait on the prefetch happens here, ~a full compute phase later)
    asm volatile("s_waitcnt lgkmcnt(0)" ::: "memory");
    __builtin_amdgcn_s_barrier();
    if (ks + 1 < nks) {
      *(u16x8*)&sK [kr][kc]      = kg0; *(u16x8*)&sK [kr][kc + 8]  = kg1;
      *(u16x8*)&sK [kr][kc + 16] = kg2; *(u16x8*)&sK [kr][kc + 24] = kg3;
      *(u16x8*)&sVt[vr][vc]      = vg0; *(u16x8*)&sVt[vr][vc + 8]  = vg1;
      *(u16x8*)&sVt[vr][vc + 16] = vg2; *(u16x8*)&sVt[vr][vc + 24] = vg3;
    }
  }

  // epilogue: reduce l_s across fq-slices (moved out of the tile loop),
  // then O /= l, write bf16 [token][h*64 + d]
  l_s += __shfl_xor(l_s, 16, 64);
  l_s += __shfl_xor(l_s, 32, 64);
  #pragma unroll
  for (int r = 0; r < 4; ++r) {
    const float il = 1.0f / __shfl(l_s, fq*4 + r, 64);
    const int q = t0 + w*16 + fq*4 + r;
    #pragma unroll
    for (int dt = 0; dt < 4; ++dt)
      out[(size_t)(b*T_ + q)*C_ + h*HS_ + dt*16 + l15] = f2bf(oacc[dt][r] * il);
  }
}

extern "C" void kernel_launch(void* const* d_in, const int* in_sizes, int n_in,
                              void* d_out, int out_size, void* d_ws, size_t ws_size,
                              hipStream_t stream)
{
  const float* x   = (const float*)d_in[0];
  const float* Wq  = (const float*)d_in[1];
  const float* Wk  = (const float*)d_in[2];
  const float* Wv  = (const float*)d_in[3];
  const float* Wo  = (const float*)d_in[4];
  const float* bo  = (const float*)d_in[5];
  const float* W1  = (const float*)d_in[6];
  const float* b1  = (const float*)d_in[7];
  const float* W2  = (const float*)d_in[8];
  const float* b2  = (const float*)d_in[9];
  const float* g1  = (const float*)d_in[10];
  const float* be1 = (const float*)d_in[11];
  const float* g2  = (const float*)d_in[12];
  const float* be2 = (const float*)d_in[13];
  float* out = (float*)d_out;

  // Workspace (96 MB peak, liveness-based reuse):
  char* ws = (char*)d_ws;
  unsigned short* BtQKV = (unsigned short*)(ws + (size_t) 0*MB);  // 6MB
  unsigned short* BtWo  = (unsigned short*)(ws + (size_t) 6*MB);  // 2MB
  unsigned short* BtW1  = (unsigned short*)(ws + (size_t) 8*MB);  // 8MB
  unsigned short* BtW2  = (unsigned short*)(ws + (size_t)16*MB);  // 8MB
  unsigned short* lnb   = (unsigned short*)(ws + (size_t)24*MB);  // 8MB
  unsigned short* qkvb  = (unsigned short*)(ws + (size_t)32*MB);  // [4096][3072] 24MB
  unsigned short* vtb   = (unsigned short*)(ws + (size_t)56*MB);  // [32][64][2048] 8MB
  unsigned short* attnb = (unsigned short*)(ws + (size_t)64*MB);  // 8MB
  float*          x2    = (float*)         (ws + (size_t)32*MB);  // 16MB (qkv dead)
  unsigned short* hb    = (unsigned short*)(ws + (size_t)32*MB);  // 32MB (x2,vt dead)
  // split-K bf16 partials for W2: [4][4096][1024] bf16 = 32 MB (attnb dead).
  unsigned short* pk4   = (unsigned short*)(ws + (size_t)64*MB);  // 32MB

  dim3 blk(256);
  dim3 blk512(512);

  // Weight transposes (QKV fused into one dispatch: z = which*16 + head)
  transpose_cast_qkv<<<dim3(HS_/32, C_/32, 3*H_), blk, 0, stream>>>(Wq, Wk, Wv, BtQKV);
  transpose_cast<<<dim3(C_/32,  C_/32, 1),  blk, 0, stream>>>(Wo, BtWo, C_, C_);
  transpose_cast<<<dim3(4*C_/32,C_/32, 1),  blk, 0, stream>>>(W1, BtW1, C_, 4*C_);
  transpose_cast<<<dim3(C_/32,4*C_/32, 1),  blk, 0, stream>>>(W2, BtW2, 4*C_, C_);

  ln_kernel<<<dim3(N_ROWS), blk, 0, stream>>>(x, g1, be1, lnb);

  // Fused QKV GEMM -> bf16 [4096][3072]   (128x256 v3, 32x12 = 384 blocks)
  gemm256<false,false><<<dim3(N_ROWS/128, 3072/256, 1), blk512, 0, stream>>>(
      lnb, BtQKV, nullptr, qkvb, N_ROWS, 3072, C_, C_);

  // V transpose -> vt[bh][d][t]
  v_transpose<<<dim3(T_/64, B_*H_), blk, 0, stream>>>(qkvb, vtb);

  // MFMA flash attention v5 -> bf16 attnb  (32 bh x 32 qt = 1024 blocks)
  attn_mfma<<<dim3(B_*H_, T_/64), blk, 0, stream>>>(qkvb, vtb, attnb);

  // Wo GEMM + bias + residual(ln1) -> fp32 x2   (128x64 2-phase, 512 blocks)
  gemm_bf16<64,false,false,true,true><<<dim3(N_ROWS/128, C_/64), blk, 0, stream>>>(
      attnb, BtWo, bo, lnb, x2, N_ROWS, C_, C_);

  // LN2
  ln_kernel<<<dim3(N_ROWS), blk, 0, stream>>>(x2, g2, be2, lnb);

  // W1 GEMM + bias + ReLU -> bf16 hb   (128x256 v3, 32x16 = 512 blocks, 2/CU)
  gemm256<true,true><<<dim3(N_ROWS/128, 4*C_/256, 1), blk512, 0, stream>>>(
      lnb, BtW1, b1, hb, N_ROWS, 4*C_, C_, C_);

  // W2 GEMM split-K=4 -> bf16 partials  (128x256 v3, 32x4x4 = 512 blocks, 2/CU)
  gemm256<false,false><<<dim3(N_ROWS/128, C_/256, 4), blk512, 0, stream>>>(
      hb, BtW2, nullptr, pk4, N_ROWS, C_, 4*C_, C_);

  // reduce: out = sum(partials) + b2 + residual(ln2)
  splitk_reduce<4><<<dim3((N_ROWS * C_) / (256 * 4)), blk, 0, stream>>>(
      pk4, b2, lnb, out);
}